// Round 13
// baseline (3942.350 us; speedup 1.0000x reference)
//
#include <hip/hip_runtime.h>
#include <hip/hip_bf16.h>

#define B_ 32
#define D_ 384
#define N_ 196
#define NH_ 8
#define HD_ 48
#define L_ 24

typedef __bf16 bf16x8 __attribute__((ext_vector_type(8)));
typedef __bf16 bf16x4 __attribute__((ext_vector_type(4)));
typedef float f32x4 __attribute__((ext_vector_type(4)));

__device__ __forceinline__ float gelu_f(float v){
    return 0.5f * v * (1.0f + erff(v * 0.70710678118654752f));
}

// ---------------- fp32 -> bf16 bulk convert ----------------
__global__ __launch_bounds__(256) void cvt_bf(const float* __restrict__ s, __bf16* __restrict__ d, long n){
    long i = ((long)blockIdx.x * 256 + threadIdx.x) * 8;
    if (i >= n) return;
    float4 a = *reinterpret_cast<const float4*>(s + i);
    float4 b = *reinterpret_cast<const float4*>(s + i + 4);
    bf16x8 r;
    r[0] = (__bf16)a.x; r[1] = (__bf16)a.y; r[2] = (__bf16)a.z; r[3] = (__bf16)a.w;
    r[4] = (__bf16)b.x; r[5] = (__bf16)b.y; r[6] = (__bf16)b.z; r[7] = (__bf16)b.w;
    *reinterpret_cast<bf16x8*>(d + i) = r;
}

// fp32 -> bf16 with row padding (zero rows >= rows)
__global__ __launch_bounds__(256) void cvt_pad(const float* __restrict__ s, __bf16* __restrict__ d,
                                               int rows, int K, int rows_pad){
    int id = blockIdx.x * 256 + threadIdx.x;
    if (id >= rows_pad * K) return;
    int r = id / K;
    d[id] = (r < rows) ? (__bf16)s[id] : (__bf16)0.f;
}

// ---------------- conv weight reorder: W'[co][tap*Ci+ci] (bf16, K padded) ----------------
__global__ __launch_bounds__(256) void wprep(const float* __restrict__ w, __bf16* __restrict__ W2,
                                             int Co, int Ci, int Kpad){
    int id = blockIdx.x * 256 + threadIdx.x;
    if (id >= Co * Kpad) return;
    int co = id / Kpad, k = id - co * Kpad;
    float v = 0.f;
    if (k < 9 * Ci){
        int tap = k / Ci, ci = k - tap * Ci;
        v = w[((long)co * Ci + ci) * 9 + tap];
    }
    W2[id] = (__bf16)v;
}

// ---------------- im2col for conv1 (fp32 NCHW input) -> A[pix][32] bf16 ----------------
__global__ __launch_bounds__(256) void im2col_x(const float* __restrict__ x, __bf16* __restrict__ A){
    int id = blockIdx.x * 256 + threadIdx.x;
    if (id >= 401408) return;
    int ox = id % 112; int t1 = id / 112; int oy = t1 % 112; int b = t1 / 112;
    __bf16 buf[32];
    #pragma unroll
    for (int i = 0; i < 32; i++) buf[i] = (__bf16)0.f;
    const float* xb = x + (long)b * 3 * 224 * 224;
    #pragma unroll
    for (int tap = 0; tap < 9; tap++){
        int ky = tap / 3, kx = tap % 3;
        int iy = oy * 2 - 1 + ky, ix = ox * 2 - 1 + kx;
        if ((unsigned)iy < 224u && (unsigned)ix < 224u){
            #pragma unroll
            for (int ci = 0; ci < 3; ci++)
                buf[tap * 3 + ci] = (__bf16)xb[((long)ci * 224 + iy) * 224 + ix];
        }
    }
    __bf16* dst = A + (long)id * 32;
    #pragma unroll
    for (int i = 0; i < 4; i++)
        *reinterpret_cast<bf16x8*>(dst + i * 8) = *reinterpret_cast<bf16x8*>(buf + i * 8);
}

// ---------------- conv GEMM for conv1: 128x128 tile, BK=32, fused BN+GELU ----------------
template<int GELU, int POSOUT>
__global__ __launch_bounds__(256) void gemm_conv(const __bf16* __restrict__ A, int Kpad,
                                                 const __bf16* __restrict__ W,
                                                 const float* __restrict__ g, const float* __restrict__ bb,
                                                 void* __restrict__ Cv, int N,
                                                 const float* __restrict__ pos){
    __shared__ __align__(16) char smem[20480];
    char* Ab = smem;
    char* Bb = smem + 10240;
    const int tid  = threadIdx.x;
    const int lane = tid & 63;
    const int wn   = (tid >> 6) & 1;
    const int wm   = tid >> 7;
    const int row0 = blockIdx.x * 128;
    const int col0 = blockIdx.y * 128;
    const int hi = lane >> 4, lo = lane & 15;
    f32x4 acc[4][4] = {};
    auto loadA = [&](int kk, int i)->bf16x8 {
        int p = i * 256 + tid;
        int r = p >> 2, cq = p & 3;
        return *reinterpret_cast<const bf16x8*>(A + (long)(row0 + r) * Kpad + kk + cq * 8);
    };
    auto loadB = [&](int kk, int i)->bf16x8 {
        int p = i * 256 + tid;
        int r = p >> 2, cq = p & 3;
        int gc = col0 + r;
        bf16x8 vw{};
        if (gc < N) vw = *reinterpret_cast<const bf16x8*>(W + (long)gc * Kpad + kk + cq * 8);
        return vw;
    };
    bf16x8 vaC0 = loadA(0, 0), vaC1 = loadA(0, 1);
    bf16x8 vwC0 = loadB(0, 0), vwC1 = loadB(0, 1);
    for (int k0 = 0; k0 < Kpad; k0 += 32){
        #pragma unroll
        for (int i = 0; i < 2; i++){
            int p = i * 256 + tid;
            int r = p >> 2, cq = p & 3;
            *reinterpret_cast<bf16x8*>(Ab + r * 80 + cq * 16) = i ? vaC1 : vaC0;
            *reinterpret_cast<bf16x8*>(Bb + r * 80 + cq * 16) = i ? vwC1 : vwC0;
        }
        __syncthreads();
        int kn = (k0 + 32 < Kpad) ? k0 + 32 : k0;
        bf16x8 vaN0 = loadA(kn, 0), vaN1 = loadA(kn, 1);
        bf16x8 vwN0 = loadB(kn, 0), vwN1 = loadB(kn, 1);
        bf16x8 af[4], bfr[4];
        #pragma unroll
        for (int m = 0; m < 4; m++)
            af[m] = *reinterpret_cast<const bf16x8*>(Ab + (wm * 64 + m * 16 + lo) * 80 + hi * 16);
        #pragma unroll
        for (int n = 0; n < 4; n++)
            bfr[n] = *reinterpret_cast<const bf16x8*>(Bb + (wn * 64 + n * 16 + lo) * 80 + hi * 16);
        #pragma unroll
        for (int m = 0; m < 4; m++)
            #pragma unroll
            for (int n = 0; n < 4; n++)
                acc[m][n] = __builtin_amdgcn_mfma_f32_16x16x32_bf16(af[m], bfr[n], acc[m][n], 0, 0, 0);
        __syncthreads();
        vaC0 = vaN0; vaC1 = vaN1; vwC0 = vwN0; vwC1 = vwN1;
    }
    float* Cf = (float*)Cv;
    __bf16* Cb = (__bf16*)Cv;
    #pragma unroll
    for (int m = 0; m < 4; m++){
        #pragma unroll
        for (int n = 0; n < 4; n++){
            int row = row0 + wm * 64 + m * 16 + hi * 4;
            int col = col0 + wn * 64 + n * 16 + lo;
            if (col >= N) continue;
            float scale = g[col] * rsqrtf(1.0f + 1e-5f);
            float bv = bb[col];
            #pragma unroll
            for (int j = 0; j < 4; j++){
                float v = acc[m][n][j] * scale + bv;
                if (GELU) v = gelu_f(v);
                if (POSOUT)
                    Cf[(long)(row + j) * 384 + col] = v + pos[((row + j) % 196) * 384 + col];
                else
                    Cb[(long)(row + j) * N + col] = (__bf16)v;
            }
        }
    }
}

// ---------------- implicit-im2col conv GEMM (conv2/3/4): gathers A from [pix][C] bf16 ----------------
template<int GELU, int POSOUT, int C, int Hi, int Wi, int Ho, int Wo>
__global__ __launch_bounds__(256) void gemm_cig(const __bf16* __restrict__ in, int Kpad,
                                                const __bf16* __restrict__ W,
                                                const float* __restrict__ g, const float* __restrict__ bb,
                                                void* __restrict__ Cv, int N,
                                                const float* __restrict__ pos){
    __shared__ __align__(16) char smem[36864];
    char* Ab = smem;
    char* Bb = smem + 18432;
    const int tid  = threadIdx.x;
    const int lane = tid & 63;
    const int wn   = (tid >> 6) & 1;
    const int wm   = tid >> 7;
    const int row0 = blockIdx.x * 128;
    const int col0 = blockIdx.y * 128;
    const int hi = lane >> 4, lo = lane & 15;
    f32x4 acc[4][4] = {};
    auto loadA = [&](int kk, int i)->bf16x8 {
        int p = i * 256 + tid;
        int r = p >> 3, cq = p & 7;
        int koff = kk + cq * 8;
        int tap = koff / C;
        int ci = koff - tap * C;
        bf16x8 va{};
        if (tap < 9){
            int pix = row0 + r;
            int b = pix / (Ho * Wo);
            int rem = pix - b * (Ho * Wo);
            int oy = rem / Wo, ox = rem - oy * Wo;
            int iy = oy * 2 - 1 + tap / 3, ix = ox * 2 - 1 + tap % 3;
            if ((unsigned)iy < (unsigned)Hi && (unsigned)ix < (unsigned)Wi)
                va = *reinterpret_cast<const bf16x8*>(in + (((long)b * Hi + iy) * Wi + ix) * C + ci);
        }
        return va;
    };
    auto loadB = [&](int kk, int i)->bf16x8 {
        int p = i * 256 + tid;
        int r = p >> 3, cq = p & 7;
        int gc = col0 + r;
        bf16x8 vw{};
        if (gc < N) vw = *reinterpret_cast<const bf16x8*>(W + (long)gc * Kpad + kk + cq * 8);
        return vw;
    };
    bf16x8 vaC[4], vwC[4];
    #pragma unroll
    for (int i = 0; i < 4; i++){ vaC[i] = loadA(0, i); vwC[i] = loadB(0, i); }
    for (int k0 = 0; k0 < Kpad; k0 += 64){
        #pragma unroll
        for (int i = 0; i < 4; i++){
            int p = i * 256 + tid;
            int r = p >> 3, cq = p & 7;
            *reinterpret_cast<bf16x8*>(Ab + r * 144 + cq * 16) = vaC[i];
            *reinterpret_cast<bf16x8*>(Bb + r * 144 + cq * 16) = vwC[i];
        }
        __syncthreads();
        int kn = (k0 + 64 < Kpad) ? k0 + 64 : k0;
        bf16x8 vaN[4], vwN[4];
        #pragma unroll
        for (int i = 0; i < 4; i++){ vaN[i] = loadA(kn, i); vwN[i] = loadB(kn, i); }
        bf16x8 af[2][4], bfr[2][4];
        #pragma unroll
        for (int m = 0; m < 4; m++){
            af[0][m] = *reinterpret_cast<const bf16x8*>(Ab + (wm * 64 + m * 16 + lo) * 144 + hi * 16);
            af[1][m] = *reinterpret_cast<const bf16x8*>(Ab + (wm * 64 + m * 16 + lo) * 144 + 64 + hi * 16);
        }
        #pragma unroll
        for (int n = 0; n < 4; n++){
            bfr[0][n] = *reinterpret_cast<const bf16x8*>(Bb + (wn * 64 + n * 16 + lo) * 144 + hi * 16);
            bfr[1][n] = *reinterpret_cast<const bf16x8*>(Bb + (wn * 64 + n * 16 + lo) * 144 + 64 + hi * 16);
        }
        #pragma unroll
        for (int kc = 0; kc < 2; kc++)
            #pragma unroll
            for (int m = 0; m < 4; m++)
                #pragma unroll
                for (int n = 0; n < 4; n++)
                    acc[m][n] = __builtin_amdgcn_mfma_f32_16x16x32_bf16(af[kc][m], bfr[kc][n], acc[m][n], 0, 0, 0);
        __syncthreads();
        #pragma unroll
        for (int i = 0; i < 4; i++){ vaC[i] = vaN[i]; vwC[i] = vwN[i]; }
    }
    float* Cf = (float*)Cv;
    __bf16* Cb = (__bf16*)Cv;
    #pragma unroll
    for (int m = 0; m < 4; m++){
        #pragma unroll
        for (int n = 0; n < 4; n++){
            int row = row0 + wm * 64 + m * 16 + hi * 4;
            int col = col0 + wn * 64 + n * 16 + lo;
            if (col >= N) continue;
            float scale = g[col] * rsqrtf(1.0f + 1e-5f);
            float bv = bb[col];
            #pragma unroll
            for (int j = 0; j < 4; j++){
                float v = acc[m][n][j] * scale + bv;
                if (GELU) v = gelu_f(v);
                if (POSOUT)
                    Cf[(long)(row + j) * 384 + col] = v + pos[((row + j) % 196) * 384 + col];
                else
                    Cb[(long)(row + j) * N + col] = (__bf16)v;
            }
        }
    }
}

// ---------------- bf16 MFMA GEMM, 128x128 tile, 4 waves (2x2), BK=64, bf16 out ----------------
// M%128==0, N%128==0, K%64==0. MODE 0: plain; 1: gelu.
template<int MODE>
__global__ __launch_bounds__(256) void gemm_bb4(const __bf16* __restrict__ A, long lda,
                                                const __bf16* __restrict__ W, int Kw,
                                                const float* __restrict__ bias,
                                                __bf16* __restrict__ C, long ldc,
                                                int K){
    __shared__ __align__(16) char smem[36864];
    char* Ab = smem;             // 128 rows x 144B
    char* Bb = smem + 18432;     // 128 rows x 144B
    const int tid  = threadIdx.x;
    const int lane = tid & 63;
    const int wn   = (tid >> 6) & 1;
    const int wm   = tid >> 7;
    const int row0 = blockIdx.x * 128;
    const int col0 = blockIdx.y * 128;
    const int hi = lane >> 4, lo = lane & 15;
    f32x4 acc[4][4] = {};
    auto loadA = [&](int kk, int i)->bf16x8 {
        int p = i * 256 + tid;
        int r = p >> 3, cq = p & 7;
        return *reinterpret_cast<const bf16x8*>(A + (long)(row0 + r) * lda + kk + cq * 8);
    };
    auto loadB = [&](int kk, int i)->bf16x8 {
        int p = i * 256 + tid;
        int r = p >> 3, cq = p & 7;
        return *reinterpret_cast<const bf16x8*>(W + (long)(col0 + r) * Kw + kk + cq * 8);
    };
    bf16x8 vaC[4], vwC[4];
    #pragma unroll
    for (int i = 0; i < 4; i++){ vaC[i] = loadA(0, i); vwC[i] = loadB(0, i); }
    for (int k0 = 0; k0 < K; k0 += 64){
        #pragma unroll
        for (int i = 0; i < 4; i++){
            int p = i * 256 + tid;
            int r = p >> 3, cq = p & 7;
            *reinterpret_cast<bf16x8*>(Ab + r * 144 + cq * 16) = vaC[i];
            *reinterpret_cast<bf16x8*>(Bb + r * 144 + cq * 16) = vwC[i];
        }
        __syncthreads();
        int kn = (k0 + 64 < K) ? k0 + 64 : k0;
        bf16x8 vaN[4], vwN[4];
        #pragma unroll
        for (int i = 0; i < 4; i++){ vaN[i] = loadA(kn, i); vwN[i] = loadB(kn, i); }
        bf16x8 af[2][4], bfr[2][4];
        #pragma unroll
        for (int m = 0; m < 4; m++){
            af[0][m] = *reinterpret_cast<const bf16x8*>(Ab + (wm * 64 + m * 16 + lo) * 144 + hi * 16);
            af[1][m] = *reinterpret_cast<const bf16x8*>(Ab + (wm * 64 + m * 16 + lo) * 144 + 64 + hi * 16);
        }
        #pragma unroll
        for (int n = 0; n < 4; n++){
            bfr[0][n] = *reinterpret_cast<const bf16x8*>(Bb + (wn * 64 + n * 16 + lo) * 144 + hi * 16);
            bfr[1][n] = *reinterpret_cast<const bf16x8*>(Bb + (wn * 64 + n * 16 + lo) * 144 + 64 + hi * 16);
        }
        #pragma unroll
        for (int kc = 0; kc < 2; kc++)
            #pragma unroll
            for (int m = 0; m < 4; m++)
                #pragma unroll
                for (int n = 0; n < 4; n++)
                    acc[m][n] = __builtin_amdgcn_mfma_f32_16x16x32_bf16(af[kc][m], bfr[kc][n], acc[m][n], 0, 0, 0);
        __syncthreads();
        #pragma unroll
        for (int i = 0; i < 4; i++){ vaC[i] = vaN[i]; vwC[i] = vwN[i]; }
    }
    #pragma unroll
    for (int m = 0; m < 4; m++){
        #pragma unroll
        for (int n = 0; n < 4; n++){
            int row = row0 + wm * 64 + m * 16 + hi * 4;
            int col = col0 + wn * 64 + n * 16 + lo;
            float bv = bias[col];
            #pragma unroll
            for (int j = 0; j < 4; j++){
                float v = acc[m][n][j] + bv;
                if (MODE == 1) v = gelu_f(v);
                C[(long)(row + j) * ldc + col] = (__bf16)v;
            }
        }
    }
}

// ---------------- LayerNorm over D=384, fp32 out ----------------
__global__ __launch_bounds__(128) void ln384(const float* __restrict__ x, long xstride,
                                             const float* __restrict__ w, const float* __restrict__ b,
                                             float* __restrict__ y, long ystride){
    long row = blockIdx.x;
    int tid = threadIdx.x;
    const float* xr = x + row * xstride;
    float v0 = xr[tid], v1 = xr[tid + 128], v2 = xr[tid + 256];
    float s = v0 + v1 + v2;
    float ss = v0 * v0 + v1 * v1 + v2 * v2;
    for (int off = 32; off; off >>= 1){ s += __shfl_down(s, off); ss += __shfl_down(ss, off); }
    __shared__ float rs[2], rss[2];
    if ((tid & 63) == 0){ rs[tid >> 6] = s; rss[tid >> 6] = ss; }
    __syncthreads();
    float S = rs[0] + rs[1], SS = rss[0] + rss[1];
    float m = S * (1.0f / 384.0f);
    float var = SS * (1.0f / 384.0f) - m * m;
    float r = rsqrtf(var + 1e-5f);
    float* yr = y + row * ystride;
    yr[tid]       = (v0 - m) * r * w[tid]       + b[tid];
    yr[tid + 128] = (v1 - m) * r * w[tid + 128] + b[tid + 128];
    yr[tid + 256] = (v2 - m) * r * w[tid + 256] + b[tid + 256];
}

// ---------------- LayerNorm, bf16 out (row stride 384) ----------------
__global__ __launch_bounds__(128) void ln384_bf(const float* __restrict__ x,
                                                const float* __restrict__ w, const float* __restrict__ b,
                                                __bf16* __restrict__ y){
    long row = blockIdx.x;
    int tid = threadIdx.x;
    const float* xr = x + row * 384;
    float v0 = xr[tid], v1 = xr[tid + 128], v2 = xr[tid + 256];
    float s = v0 + v1 + v2;
    float ss = v0 * v0 + v1 * v1 + v2 * v2;
    for (int off = 32; off; off >>= 1){ s += __shfl_down(s, off); ss += __shfl_down(ss, off); }
    __shared__ float rs[2], rss[2];
    if ((tid & 63) == 0){ rs[tid >> 6] = s; rss[tid >> 6] = ss; }
    __syncthreads();
    float S = rs[0] + rs[1], SS = rss[0] + rss[1];
    float m = S * (1.0f / 384.0f);
    float var = SS * (1.0f / 384.0f) - m * m;
    float r = rsqrtf(var + 1e-5f);
    __bf16* yr = y + row * 384;
    yr[tid]       = (__bf16)((v0 - m) * r * w[tid]       + b[tid]);
    yr[tid + 128] = (__bf16)((v1 - m) * r * w[tid + 128] + b[tid + 128]);
    yr[tid + 256] = (__bf16)((v2 - m) * r * w[tid + 256] + b[tid + 256]);
}

// ---------------- t += g1*o2 ; ht = LN3(t) transposed (bf16) ----------------
__global__ __launch_bounds__(128) void proj_res_lnt(const __bf16* __restrict__ o2,
                                                    const float* __restrict__ g1,
                                                    float* __restrict__ t,
                                                    const float* __restrict__ n3w, const float* __restrict__ n3b,
                                                    __bf16* __restrict__ ht){
    long row = blockIdx.x;
    int tid = threadIdx.x;
    int c0 = tid * 4;
    float v[4] = {0.f, 0.f, 0.f, 0.f};
    if (tid < 96){
        float4 tv = *reinterpret_cast<const float4*>(t + row * 384 + c0);
        bf16x4 ov = *reinterpret_cast<const bf16x4*>(o2 + row * 384 + c0);
        v[0] = tv.x + g1[c0 + 0] * (float)ov[0];
        v[1] = tv.y + g1[c0 + 1] * (float)ov[1];
        v[2] = tv.z + g1[c0 + 2] * (float)ov[2];
        v[3] = tv.w + g1[c0 + 3] * (float)ov[3];
        *reinterpret_cast<float4*>(t + row * 384 + c0) = make_float4(v[0], v[1], v[2], v[3]);
    }
    float s = v[0] + v[1] + v[2] + v[3];
    float ss = v[0] * v[0] + v[1] * v[1] + v[2] * v[2] + v[3] * v[3];
    for (int off = 32; off; off >>= 1){ s += __shfl_down(s, off); ss += __shfl_down(ss, off); }
    __shared__ float rs[2], rss[2];
    if ((tid & 63) == 0){ rs[tid >> 6] = s; rss[tid >> 6] = ss; }
    __syncthreads();
    float S = rs[0] + rs[1], SS = rss[0] + rss[1];
    float m = S * (1.0f / 384.0f);
    float var = SS * (1.0f / 384.0f) - m * m;
    float r = rsqrtf(var + 1e-5f);
    if (tid < 96){
        int b = (int)(row / 196), n = (int)(row % 196);
        __bf16* yb = ht + ((long)b * 384) * 196 + n;
        #pragma unroll
        for (int j = 0; j < 4; j++){
            int c = c0 + j;
            yb[(long)c * 196] = (__bf16)((v[j] - m) * r * n3w[c] + n3b[c]);
        }
    }
}

// ---------------- t += hadd ; h = LN2(t) bf16 ----------------
__global__ __launch_bounds__(128) void ln2res(float* __restrict__ t,
                                              const __bf16* __restrict__ hadd,
                                              const float* __restrict__ n2w, const float* __restrict__ n2b,
                                              __bf16* __restrict__ h){
    long row = blockIdx.x;
    int tid = threadIdx.x;
    int c0 = tid * 4;
    float v[4] = {0.f, 0.f, 0.f, 0.f};
    if (tid < 96){
        float4 tv = *reinterpret_cast<const float4*>(t + row * 384 + c0);
        bf16x4 hv = *reinterpret_cast<const bf16x4*>(hadd + row * 384 + c0);
        v[0] = tv.x + (float)hv[0];
        v[1] = tv.y + (float)hv[1];
        v[2] = tv.z + (float)hv[2];
        v[3] = tv.w + (float)hv[3];
        *reinterpret_cast<float4*>(t + row * 384 + c0) = make_float4(v[0], v[1], v[2], v[3]);
    }
    float s = v[0] + v[1] + v[2] + v[3];
    float ss = v[0] * v[0] + v[1] * v[1] + v[2] * v[2] + v[3] * v[3];
    for (int off = 32; off; off >>= 1){ s += __shfl_down(s, off); ss += __shfl_down(ss, off); }
    __shared__ float rs[2], rss[2];
    if ((tid & 63) == 0){ rs[tid >> 6] = s; rss[tid >> 6] = ss; }
    __syncthreads();
    float S = rs[0] + rs[1], SS = rss[0] + rss[1];
    float m = S * (1.0f / 384.0f);
    float var = SS * (1.0f / 384.0f) - m * m;
    float r = rsqrtf(var + 1e-5f);
    if (tid < 96){
        bf16x4 o;
        #pragma unroll
        for (int j = 0; j < 4; j++){
            int c = c0 + j;
            o[j] = (__bf16)((v[j] - m) * r * n2w[c] + n2b[c]);
        }
        *reinterpret_cast<bf16x4*>(h + row * 384 + c0) = o;
    }
}

// ---------------- t += g2*f2 ; h = LN1next(t) bf16 ----------------
__global__ __launch_bounds__(128) void fc2_res_ln(const __bf16* __restrict__ f2,
                                                  const float* __restrict__ g2,
                                                  float* __restrict__ t,
                                                  const float* __restrict__ n1w, const float* __restrict__ n1b,
                                                  __bf16* __restrict__ h){
    long row = blockIdx.x;
    int tid = threadIdx.x;
    int c0 = tid * 4;
    float v[4] = {0.f, 0.f, 0.f, 0.f};
    if (tid < 96){
        float4 tv = *reinterpret_cast<const float4*>(t + row * 384 + c0);
        bf16x4 fv = *reinterpret_cast<const bf16x4*>(f2 + row * 384 + c0);
        v[0] = tv.x + g2[c0 + 0] * (float)fv[0];
        v[1] = tv.y + g2[c0 + 1] * (float)fv[1];
        v[2] = tv.z + g2[c0 + 2] * (float)fv[2];
        v[3] = tv.w + g2[c0 + 3] * (float)fv[3];
        *reinterpret_cast<float4*>(t + row * 384 + c0) = make_float4(v[0], v[1], v[2], v[3]);
    }
    float s = v[0] + v[1] + v[2] + v[3];
    float ss = v[0] * v[0] + v[1] * v[1] + v[2] * v[2] + v[3] * v[3];
    for (int off = 32; off; off >>= 1){ s += __shfl_down(s, off); ss += __shfl_down(ss, off); }
    __shared__ float rs[2], rss[2];
    if ((tid & 63) == 0){ rs[tid >> 6] = s; rss[tid >> 6] = ss; }
    __syncthreads();
    float S = rs[0] + rs[1], SS = rss[0] + rss[1];
    float m = S * (1.0f / 384.0f);
    float var = SS * (1.0f / 384.0f) - m * m;
    float r = rsqrtf(var + 1e-5f);
    if (tid < 96){
        bf16x4 o;
        #pragma unroll
        for (int j = 0; j < 4; j++){
            int c = c0 + j;
            o[j] = (__bf16)((v[j] - m) * r * n1w[c] + n1b[c]);
        }
        *reinterpret_cast<bf16x4*>(h + row * 384 + c0) = o;
    }
}

// ---------------- bf16 MFMA GEMM, 64x128 tile, 4 waves, BK=64, 2-stage prefetch ----------------
// (used for CA phase + head: guards, fp32-A option)
template<int MODE, int OUTBF, int ACVT, int GUARD, int NGUARD>
__global__ __launch_bounds__(256) void gemm_bb2(const void* __restrict__ Av, long lda,
                                                const __bf16* __restrict__ W, int Kw,
                                                const float* __restrict__ bias,
                                                void* __restrict__ Cv, long ldc,
                                                int K, int M, int Ncols){
    __shared__ __align__(16) char smem[27648];
    char* Ab = smem;            // 64 rows x 144B
    char* Bb = smem + 9216;     // 128 rows x 144B
    const int tid = threadIdx.x;
    const int lane = tid & 63;
    const int wn = tid >> 6;
    const int row0 = blockIdx.x * 64;
    const int col0 = blockIdx.y * 128;
    const int hi = lane >> 4, lo = lane & 15;
    const __bf16* Abf = (const __bf16*)Av;
    const float* Af = (const float*)Av;
    f32x4 acc[4][2] = {};
    auto loadA = [&](int kk, int i)->bf16x8 {
        int p = i * 256 + tid;
        int r = p >> 3, cq = p & 7;
        bf16x8 va{};
        int grow = row0 + r;
        if (!GUARD || grow < M){
            long ai = (long)grow * lda + kk + cq * 8;
            if (ACVT){
                float4 a0 = *reinterpret_cast<const float4*>(Af + ai);
                float4 a1 = *reinterpret_cast<const float4*>(Af + ai + 4);
                va[0] = (__bf16)a0.x; va[1] = (__bf16)a0.y; va[2] = (__bf16)a0.z; va[3] = (__bf16)a0.w;
                va[4] = (__bf16)a1.x; va[5] = (__bf16)a1.y; va[6] = (__bf16)a1.z; va[7] = (__bf16)a1.w;
            } else {
                va = *reinterpret_cast<const bf16x8*>(Abf + ai);
            }
        }
        return va;
    };
    auto loadB = [&](int kk, int i)->bf16x8 {
        int p = i * 256 + tid;
        int r = p >> 3, cq = p & 7;
        return *reinterpret_cast<const bf16x8*>(W + (long)(col0 + r) * Kw + kk + cq * 8);
    };
    bf16x8 vaC[2], vwC[4];
    vaC[0] = loadA(0, 0); vaC[1] = loadA(0, 1);
    #pragma unroll
    for (int i = 0; i < 4; i++) vwC[i] = loadB(0, i);
    for (int k0 = 0; k0 < K; k0 += 64){
        #pragma unroll
        for (int i = 0; i < 2; i++){
            int p = i * 256 + tid;
            int r = p >> 3, cq = p & 7;
            *reinterpret_cast<bf16x8*>(Ab + r * 144 + cq * 16) = vaC[i];
        }
        #pragma unroll
        for (int i = 0; i < 4; i++){
            int p = i * 256 + tid;
            int r = p >> 3, cq = p & 7;
            *reinterpret_cast<bf16x8*>(Bb + r * 144 + cq * 16) = vwC[i];
        }
        __syncthreads();
        int kn = (k0 + 64 < K) ? k0 + 64 : k0;
        bf16x8 vaN[2], vwN[4];
        vaN[0] = loadA(kn, 0); vaN[1] = loadA(kn, 1);
        #pragma unroll
        for (int i = 0; i < 4; i++) vwN[i] = loadB(kn, i);
        bf16x8 af[2][4], bfr[2][2];
        #pragma unroll
        for (int m = 0; m < 4; m++){
            af[0][m] = *reinterpret_cast<const bf16x8*>(Ab + (m * 16 + lo) * 144 + hi * 16);
            af[1][m] = *reinterpret_cast<const bf16x8*>(Ab + (m * 16 + lo) * 144 + 64 + hi * 16);
        }
        #pragma unroll
        for (int n = 0; n < 2; n++){
            bfr[0][n] = *reinterpret_cast<const bf16x8*>(Bb + (wn * 32 + n * 16 + lo) * 144 + hi * 16);
            bfr[1][n] = *reinterpret_cast<const bf16x8*>(Bb + (wn * 32 + n * 16 + lo) * 144 + 64 + hi * 16);
        }
        #pragma unroll
        for (int kc = 0; kc < 2; kc++)
            #pragma unroll
            for (int m = 0; m < 4; m++)
                #pragma unroll
                for (int n = 0; n < 2; n++)
                    acc[m][n] = __builtin_amdgcn_mfma_f32_16x16x32_bf16(af[kc][m], bfr[kc][n], acc[m][n], 0, 0, 0);
        __syncthreads();
        vaC[0] = vaN[0]; vaC[1] = vaN[1];
        #pragma unroll
        for (int i = 0; i < 4; i++) vwC[i] = vwN[i];
    }
    float* Cf = (float*)Cv;
    __bf16* Cb = (__bf16*)Cv;
    #pragma unroll
    for (int m = 0; m < 4; m++){
        #pragma unroll
        for (int n = 0; n < 2; n++){
            int row = row0 + m * 16 + hi * 4;
            int col = col0 + wn * 32 + n * 16 + lo;
            if (NGUARD && col >= Ncols) continue;
            float bv = bias[col];
            #pragma unroll
            for (int j = 0; j < 4; j++){
                if (GUARD && (row + j) >= M) continue;
                float v = acc[m][n][j] + bv;
                if (MODE == 1) v = gelu_f(v);
                long ci = (long)(row + j) * ldc + col;
                if (OUTBF) Cb[ci] = (__bf16)v;
                else Cf[ci] = v;
            }
        }
    }
}

// ---------------- bf16 MFMA GEMM, 64x64 tile, 2x2 waves (32x32/wave), BK=64, bf16 out ----------------
__global__ __launch_bounds__(256) void gemm_bb3(const __bf16* __restrict__ A, long lda,
                                                const __bf16* __restrict__ W, int Kw,
                                                const float* __restrict__ bias,
                                                __bf16* __restrict__ C, long ldc,
                                                int K){
    __shared__ __align__(16) char smem[18432];
    char* Ab = smem;            // 64 rows x 144B
    char* Bb = smem + 9216;     // 64 rows x 144B
    const int tid = threadIdx.x;
    const int lane = tid & 63;
    const int wid = tid >> 6;
    const int wm = wid >> 1, wnn = wid & 1;
    const int row0 = blockIdx.x * 64;
    const int col0 = blockIdx.y * 64;
    const int hi = lane >> 4, lo = lane & 15;
    f32x4 acc[2][2] = {};
    auto loadA = [&](int kk, int i)->bf16x8 {
        int p = i * 256 + tid;
        int r = p >> 3, cq = p & 7;
        return *reinterpret_cast<const bf16x8*>(A + (long)(row0 + r) * lda + kk + cq * 8);
    };
    auto loadB = [&](int kk, int i)->bf16x8 {
        int p = i * 256 + tid;
        int r = p >> 3, cq = p & 7;
        return *reinterpret_cast<const bf16x8*>(W + (long)(col0 + r) * Kw + kk + cq * 8);
    };
    bf16x8 vaC[2], vwC[2];
    vaC[0] = loadA(0, 0); vaC[1] = loadA(0, 1);
    vwC[0] = loadB(0, 0); vwC[1] = loadB(0, 1);
    for (int k0 = 0; k0 < K; k0 += 64){
        #pragma unroll
        for (int i = 0; i < 2; i++){
            int p = i * 256 + tid;
            int r = p >> 3, cq = p & 7;
            *reinterpret_cast<bf16x8*>(Ab + r * 144 + cq * 16) = vaC[i];
            *reinterpret_cast<bf16x8*>(Bb + r * 144 + cq * 16) = vwC[i];
        }
        __syncthreads();
        int kn = (k0 + 64 < K) ? k0 + 64 : k0;
        bf16x8 vaN[2], vwN[2];
        vaN[0] = loadA(kn, 0); vaN[1] = loadA(kn, 1);
        vwN[0] = loadB(kn, 0); vwN[1] = loadB(kn, 1);
        bf16x8 af[2][2], bfr[2][2];
        #pragma unroll
        for (int m = 0; m < 2; m++){
            af[0][m] = *reinterpret_cast<const bf16x8*>(Ab + (wm * 32 + m * 16 + lo) * 144 + hi * 16);
            af[1][m] = *reinterpret_cast<const bf16x8*>(Ab + (wm * 32 + m * 16 + lo) * 144 + 64 + hi * 16);
        }
        #pragma unroll
        for (int n = 0; n < 2; n++){
            bfr[0][n] = *reinterpret_cast<const bf16x8*>(Bb + (wnn * 32 + n * 16 + lo) * 144 + hi * 16);
            bfr[1][n] = *reinterpret_cast<const bf16x8*>(Bb + (wnn * 32 + n * 16 + lo) * 144 + 64 + hi * 16);
        }
        #pragma unroll
        for (int kc = 0; kc < 2; kc++)
            #pragma unroll
            for (int m = 0; m < 2; m++)
                #pragma unroll
                for (int n = 0; n < 2; n++)
                    acc[m][n] = __builtin_amdgcn_mfma_f32_16x16x32_bf16(af[kc][m], bfr[kc][n], acc[m][n], 0, 0, 0);
        __syncthreads();
        vaC[0] = vaN[0]; vaC[1] = vaN[1]; vwC[0] = vwN[0]; vwC[1] = vwN[1];
    }
    #pragma unroll
    for (int m = 0; m < 2; m++){
        #pragma unroll
        for (int n = 0; n < 2; n++){
            int row = row0 + wm * 32 + m * 16 + hi * 4;
            int col = col0 + wnn * 32 + n * 16 + lo;
            float bv = bias[col];
            #pragma unroll
            for (int j = 0; j < 4; j++)
                C[(long)(row + j) * ldc + col] = (__bf16)(acc[m][n][j] + bv);
        }
    }
}

// ---------------- positional embedding: pos[n, d] ----------------
__global__ __launch_bounds__(384) void pos_embed(const float* __restrict__ pw, const float* __restrict__ pb,
                                                 float* __restrict__ pos){
    __shared__ float p64[64];
    int n = blockIdx.x;
    int iy = n / 14, ix = n % 14;
    int t = threadIdx.x;
    if (t < 64){
        int axis = t >> 5;
        int c = t & 31;
        int u = c >> 1;
        float coord = (axis == 0) ? (float)(iy + 1) : (float)(ix + 1);
        float val = coord / ((14.0f + 1e-6f) * 6.283185307179586f);
        float T = powf(10000.0f, (float)u / 16.0f);
        float a = val / T;
        p64[t] = (c & 1) ? cosf(a) : sinf(a);
    }
    __syncthreads();
    float acc = 0.f;
    const float* wr = pw + (long)t * 64;
    #pragma unroll 8
    for (int c = 0; c < 64; c++) acc += p64[c] * wr[c];
    pos[n * 384 + t] = acc + pb[t];
}

// ---------------- XCA attention via MFMA: one block per (b, head); V read from global ----------------
__global__ __launch_bounds__(256) void xca2(const __bf16* __restrict__ qkv, const float* __restrict__ temp,
                                            __bf16* __restrict__ o){
    __shared__ __align__(16) char smem[45056];
    __bf16* qs = (__bf16*)smem;                 // 48*232*2 = 22272
    __bf16* ks = (__bf16*)(smem + 22272);       // 22272
    float* inq = (float*)(smem + 44544);        // 192
    float* ink = (float*)(smem + 44736);        // 192
    float* att = (float*)smem;                  // overlay on qs (13056B)
    __bf16* abf = (__bf16*)(smem + 22272);      // overlay on ks (6912B)
    int bh = blockIdx.x;
    int b = bh >> 3, h = bh & 7;
    const int tid = threadIdx.x;
    const int wid = tid >> 6, lane = tid & 63;
    const int hi = lane >> 4, lo = lane & 15;
    const __bf16* base = qkv + ((long)b * 196) * 1152 + h * 48;
    bf16x8 z8 = {};
    for (int idx = tid; idx < 48 * 28; idx += 256){
        int d = idx / 28, n = 196 + idx % 28;
        qs[d * 232 + n] = (__bf16)0.f;
        ks[d * 232 + n] = (__bf16)0.f;
    }
    for (int ch = tid; ch < 196 * 6; ch += 256){
        int n = ch / 6, c = ch % 6, d0 = c * 8;
        bf16x8 q8 = *reinterpret_cast<const bf16x8*>(base + (long)n * 1152 + d0);
        bf16x8 k8 = *reinterpret_cast<const bf16x8*>(base + (long)n * 1152 + 384 + d0);
        #pragma unroll
        for (int j = 0; j < 8; j++){
            qs[(d0 + j) * 232 + n] = q8[j];
            ks[(d0 + j) * 232 + n] = k8[j];
        }
    }
    __syncthreads();
    // row norms: vectorized bf16x4 LDS reads (cols 196..223 are zero)
    for (int r = wid; r < 48; r += 4){
        float sq = 0.f, sk = 0.f;
        if (lane < 56){
            bf16x4 q4 = *reinterpret_cast<const bf16x4*>(qs + r * 232 + lane * 4);
            bf16x4 k4 = *reinterpret_cast<const bf16x4*>(ks + r * 232 + lane * 4);
            #pragma unroll
            for (int j = 0; j < 4; j++){
                float qv = (float)q4[j], kv = (float)k4[j];
                sq += qv * qv; sk += kv * kv;
            }
        }
        for (int off = 32; off; off >>= 1){ sq += __shfl_down(sq, off); sk += __shfl_down(sk, off); }
        if (lane == 0){
            inq[r] = 1.0f / fmaxf(sqrtf(sq), 1e-12f);
            ink[r] = 1.0f / fmaxf(sqrtf(sk), 1e-12f);
        }
    }
    __syncthreads();
    float tempv = temp[h];
    f32x4 qk0 = {}, qk1 = {}, qk2 = {};
    __builtin_amdgcn_s_setprio(1);
    {
        int mi = wid / 3, ni = wid % 3;
        #pragma unroll
        for (int k0 = 0; k0 < 224; k0 += 32){
            bf16x8 af = *reinterpret_cast<const bf16x8*>(qs + (mi * 16 + lo) * 232 + k0 + hi * 8);
            bf16x8 bf = *reinterpret_cast<const bf16x8*>(ks + (ni * 16 + lo) * 232 + k0 + hi * 8);
            qk0 = __builtin_amdgcn_mfma_f32_16x16x32_bf16(af, bf, qk0, 0, 0, 0);
        }
    }
    {
        int tt = wid + 4;
        int mi = tt / 3, ni = tt % 3;
        #pragma unroll
        for (int k0 = 0; k0 < 224; k0 += 32){
            bf16x8 af = *reinterpret_cast<const bf16x8*>(qs + (mi * 16 + lo) * 232 + k0 + hi * 8);
            bf16x8 bf = *reinterpret_cast<const bf16x8*>(ks + (ni * 16 + lo) * 232 + k0 + hi * 8);
            qk1 = __builtin_amdgcn_mfma_f32_16x16x32_bf16(af, bf, qk1, 0, 0, 0);
        }
    }
    if (wid == 0){
        #pragma unroll
        for (int k0 = 0; k0 < 224; k0 += 32){
            bf16x8 af = *reinterpret_cast<const bf16x8*>(qs + (2 * 16 + lo) * 232 + k0 + hi * 8);
            bf16x8 bf = *reinterpret_cast<const bf16x8*>(ks + (2 * 16 + lo) * 232 + k0 + hi * 8);
            qk2 = __builtin_amdgcn_mfma_f32_16x16x32_bf16(af, bf, qk2, 0, 0, 0);
        }
    }
    __builtin_amdgcn_s_setprio(0);
    __syncthreads();   // qs/ks reads done; overlays writable
    {
        int mi = wid / 3, ni = wid % 3;
        int e = ni * 16 + lo;
        float se = ink[e] * tempv;
        #pragma unroll
        for (int j = 0; j < 4; j++){
            int d = mi * 16 + hi * 4 + j;
            att[d * 68 + e] = qk0[j] * inq[d] * se;
        }
    }
    {
        int tt = wid + 4;
        int mi = tt / 3, ni = tt % 3;
        int e = ni * 16 + lo;
        float se = ink[e] * tempv;
        #pragma unroll
        for (int j = 0; j < 4; j++){
            int d = mi * 16 + hi * 4 + j;
            att[d * 68 + e] = qk1[j] * inq[d] * se;
        }
    }
    if (wid == 0){
        int e = 2 * 16 + lo;
        float se = ink[e] * tempv;
        #pragma unroll
        for (int j = 0; j < 4; j++){
            int d = 2 * 16 + hi * 4 + j;
            att[d * 68 + e] = qk2[j] * inq[d] * se;
        }
    }
    __syncthreads();
    if (tid < 192){
        int r = tid >> 2, q4 = tid & 3;
        const float* row = att + r * 68 + q4 * 12;
        float mx = -1e30f;
        #pragma unroll
        for (int i = 0; i < 12; i++) mx = fmaxf(mx, row[i]);
        mx = fmaxf(mx, __shfl_xor(mx, 1));
        mx = fmaxf(mx, __shfl_xor(mx, 2));
        float pv[12]; float sm = 0.f;
        #pragma unroll
        for (int i = 0; i < 12; i++){ pv[i] = expf(row[i] - mx); sm += pv[i]; }
        sm += __shfl_xor(sm, 1);
        sm += __shfl_xor(sm, 2);
        float inv = 1.0f / sm;
        #pragma unroll
        for (int i = 0; i < 12; i++) abf[r * 72 + q4 * 12 + i] = (__bf16)(pv[i] * inv);
    }
    for (int idx = tid; idx < 48 * 3; idx += 256){
        int r = idx / 3, c = 48 + (idx % 3) * 8;
        *reinterpret_cast<bf16x8*>(abf + r * 72 + c) = z8;
    }
    __syncthreads();
    // PV: A = abf (LDS), B = V from global (qkv[n][768+e], contiguous in e).
    __bf16* ob = o + ((long)b * 196) * 384 + h * 48;
    __builtin_amdgcn_s_setprio(1);
    for (int tt = wid; tt < 39; tt += 4){
        int mi = tt / 13, ni = tt % 13;
        int nB = ni * 16 + lo;
        const __bf16* vrow = base + (long)nB * 1152 + 768;
        f32x4 acc = {};
        #pragma unroll
        for (int e0 = 0; e0 < 64; e0 += 32){
            bf16x8 af = *reinterpret_cast<const bf16x8*>(abf + (mi * 16 + lo) * 72 + e0 + hi * 8);
            bf16x8 bf = *reinterpret_cast<const bf16x8*>(vrow + e0 + hi * 8);
            acc = __builtin_amdgcn_mfma_f32_16x16x32_bf16(af, bf, acc, 0, 0, 0);
        }
        int n = nB;
        if (n < 196){
            #pragma unroll
            for (int j = 0; j < 4; j++){
                int d = mi * 16 + hi * 4 + j;
                ob[(long)n * 384 + d] = (__bf16)acc[j];
            }
        }
    }
    __builtin_amdgcn_s_setprio(0);
}

// ---------------- LPI: gated output to hadd (bf16, [b,n,d]), ht bf16 in ----------------
__global__ __launch_bounds__(256) void lpi_g(const __bf16* __restrict__ ht,
                                             const float* __restrict__ w1, const float* __restrict__ b1,
                                             const float* __restrict__ bng, const float* __restrict__ bnb,
                                             const float* __restrict__ w2, const float* __restrict__ b2,
                                             const float* __restrict__ g3, __bf16* __restrict__ hadd){
    int bd = blockIdx.x;
    int d = bd % 384, b = bd / 384;
    __shared__ float p[16][16];
    __shared__ float p2[16][16];
    __shared__ float wA[9], wB[9];
    int tt = threadIdx.x;
    int yy = tt / 16, xx = tt % 16;
    p[yy][xx] = 0.f; p2[yy][xx] = 0.f;
    if (tt < 9){ wA[tt] = w1[d * 9 + tt]; wB[tt] = w2[d * 9 + tt]; }
    __syncthreads();
    if (tt < 196){
        int y = tt / 14, x = tt % 14;
        p[y + 1][x + 1] = (float)ht[((long)b * 384 + d) * 196 + tt];
    }
    __syncthreads();
    if (tt < 196){
        int y = tt / 14, x = tt % 14;
        float a = 0.f;
        #pragma unroll
        for (int ky = 0; ky < 3; ky++)
            #pragma unroll
            for (int kx = 0; kx < 3; kx++)
                a += wA[ky * 3 + kx] * p[y + ky][x + kx];
        a += b1[d];
        a = gelu_f(a);
        a = a * (bng[d] * rsqrtf(1.0f + 1e-5f)) + bnb[d];
        p2[y + 1][x + 1] = a;
    }
    __syncthreads();
    if (tt < 196){
        int y = tt / 14, x = tt % 14;
        float a = 0.f;
        #pragma unroll
        for (int ky = 0; ky < 3; ky++)
            #pragma unroll
            for (int kx = 0; kx < 3; kx++)
                a += wB[ky * 3 + kx] * p2[y + ky][x + kx];
        a += b2[d];
        hadd[((long)b * 196 + tt) * 384 + d] = (__bf16)(g3[d] * a);
    }
}

// ---------------- cls concat ----------------
__global__ __launch_bounds__(256) void concat_cls(const float* __restrict__ t, const float* __restrict__ clstok,
                                                  float* __restrict__ tc){
    long i = (long)blockIdx.x * 256 + threadIdx.x;
    if (i >= (long)B_ * 197 * 384) return;
    int d = (int)(i % 384);
    long bn = i / 384;
    int n = (int)(bn % 197);
    int b = (int)(bn / 197);
    tc[i] = (n == 0) ? clstok[d] : t[((long)b * 196 + (n - 1)) * 384 + d];
}

// ---------------- CA attention (bf16 qkv) ----------------
__global__ __launch_bounds__(256) void ca_attn(const __bf16* __restrict__ qkv, float* __restrict__ clsp){
    int bh = blockIdx.x;
    int b = bh >> 3, h = bh & 7;
    const __bf16* base = qkv + (long)b * 197 * 1152 + h * 48;
    __shared__ float q0[48];
    __shared__ float at2[197];
    __shared__ float smax, ssum;
    int tid = threadIdx.x;
    if (tid < 48) q0[tid] = (float)base[tid];
    __syncthreads();
    if (tid < 197){
        const __bf16* kr = base + (long)tid * 1152 + 384;
        float s = 0.f;
        for (int d = 0; d < 48; d++) s += q0[d] * (float)kr[d];
        at2[tid] = s * rsqrtf(48.0f);
    }
    __syncthreads();
    if (tid == 0){
        float m = -1e30f;
        for (int n = 0; n < 197; n++) m = fmaxf(m, at2[n]);
        smax = m;
    }
    __syncthreads();
    if (tid < 197) at2[tid] = expf(at2[tid] - smax);
    __syncthreads();
    if (tid == 0){
        float s = 0.f;
        for (int n = 0; n < 197; n++) s += at2[n];
        ssum = s;
    }
    __syncthreads();
    if (tid < 48){
        const __bf16* vb = base + 768 + tid;
        float s = 0.f;
        for (int n = 0; n < 197; n++) s += at2[n] * (float)vb[(long)n * 1152];
        clsp[b * 384 + h * 48 + tid] = s / ssum;
    }
}

__global__ __launch_bounds__(256) void ca_update1(const float* __restrict__ clso, const __bf16* __restrict__ hc,
                                                  const float* __restrict__ g1, float* __restrict__ tc){
    long i = (long)blockIdx.x * 256 + threadIdx.x;
    if (i >= (long)B_ * 197 * 384) return;
    int d = (int)(i % 384);
    long bn = i / 384;
    int n = (int)(bn % 197);
    int b = (int)(bn / 197);
    float add = (n == 0) ? clso[b * 384 + d] : (float)hc[i];
    tc[i] += g1[d] * add;
}

__global__ __launch_bounds__(256) void ca_update2(const float* __restrict__ cls2, const __bf16* __restrict__ hc,
                                                  const float* __restrict__ g2, float* __restrict__ tc){
    long i = (long)blockIdx.x * 256 + threadIdx.x;
    if (i >= (long)B_ * 197 * 384) return;
    int d = (int)(i % 384);
    long bn = i / 384;
    int n = (int)(bn % 197);
    int b = (int)(bn / 197);
    float hv = (float)hc[i];
    tc[i] = (n == 0) ? (g2[d] * cls2[b * 384 + d] + hv) : (hv + hv);
}

extern "C" void kernel_launch(void* const* d_in, const int* in_sizes, int n_in,
                              void* d_out, int out_size, void* d_ws, size_t ws_size,
                              hipStream_t stream){
    (void)in_sizes; (void)n_in; (void)out_size; (void)ws_size;
    const float* x      = (const float*)d_in[0];
    const float* clstok = (const float*)d_in[1];
    const float* pos_w  = (const float*)d_in[2];
    const float* pos_b  = (const float*)d_in[3];
    const float* pe_w[4] = {(const float*)d_in[4], (const float*)d_in[7], (const float*)d_in[10], (const float*)d_in[13]};
    const float* pe_g[4] = {(const float*)d_in[5], (const float*)d_in[8], (const float*)d_in[11], (const float*)d_in[14]};
    const float* pe_b[4] = {(const float*)d_in[6], (const float*)d_in[9], (const float*)d_in[12], (const float*)d_in[15]};
    const float* xqkv_w = (const float*)d_in[16];
    const float* xqkv_b = (const float*)d_in[17];
    const float* xproj_w = (const float*)d_in[18];
    const float* xproj_b = (const float*)d_in[19];
    const float* xtemp  = (const float*)d_in[20];
    const float* xn1_w = (const float*)d_in[21];
    const float* xn1_b = (const float*)d_in[22];
    const float* xn2_w = (const float*)d_in[23];
    const float* xn2_b = (const float*)d_in[24];
    const float* xn3_w = (const float*)d_in[25];
    const float* xn3_b = (const float*)d_in[26];
    const float* xfc1_w = (const float*)d_in[27];
    const float* xfc1_b = (const float*)d_in[28];
    const float* xfc2_w = (const float*)d_in[29];
    const float* xfc2_b = (const float*)d_in[30];
    const float* xlpi1_w = (const float*)d_in[31];
    const float* xlpi1_b = (const float*)d_in[32];
    const float* xlpi2_w = (const float*)d_in[33];
    const float* xlpi2_b = (const float*)d_in[34];
    const float* xbn_g = (const float*)d_in[35];
    const float* xbn_b = (const float*)d_in[36];
    const float* xg1 = (const float*)d_in[37];
    const float* xg2 = (const float*)d_in[38];
    const float* xg3 = (const float*)d_in[39];
    const float* cqkv_w = (const float*)d_in[40];
    const float* cqkv_b = (const float*)d_in[41];
    const float* cproj_w = (const float*)d_in[42];
    const float* cproj_b = (const float*)d_in[43];
    const float* cn1_w = (const float*)d_in[44];
    const float* cn1_b = (const float*)d_in[45];
    const float* cn2_w = (const float*)d_in[46];
    const float* cn2_b = (const float*)d_in[47];
    const float* cfc1_w = (const float*)d_in[48];
    const float* cfc1_b = (const float*)d_in[49];
    const float* cfc2_w = (const float*)d_in[50];
    const float* cfc2_b = (const float*)d_in[51];
    const float* cg1 = (const float*)d_in[52];
    const float* cg2 = (const float*)d_in[53];
    const float* norm_w = (const float*)d_in[54];
    const float* norm_b = (const float*)d_in[55];
    const float* head_w = (const float*)d_in[56];
    const float* head_b = (const float*)d_in[57];
    float* outp = (float*)d_out;

    float* ws = (float*)d_ws;
    // ---- conv phase buffers ----
    __bf16* A1   = (__bf16*)(ws);                  // 401408x32
    __bf16* out1 = (__bf16*)(ws + 7000000L);       // 401408x48
    __bf16* out2 = (__bf16*)(ws + 17000000L);      // 100352x96
    __bf16* out3 = (__bf16*)(ws + 25000000L);      // 25088x192
    __bf16* wcv  = (__bf16*)(ws + 36000000L);
    __bf16* W1c = wcv;
    __bf16* W2c = wcv + 1536;
    __bf16* W3c = wcv + 44544;
    __bf16* W4c = wcv + 216576;
    // ---- XCA phase ----
    __bf16* wqkv_bf = (__bf16*)(ws);
    __bf16* wproj_bf = (__bf16*)(ws + 5308416L);
    __bf16* wfc1_bf = (__bf16*)(ws + 7077888L);
    __bf16* wfc2_bf = (__bf16*)(ws + 14155776L);
    float*  t       = ws + 21233664L;
    float*  pos     = ws + 23642112L;
    __bf16* h_bf    = (__bf16*)(ws + 23717376L);
    __bf16* qkv_bf  = (__bf16*)(ws + 24921600L);
    __bf16* o_bf    = (__bf16*)(ws + 28534272L);
    __bf16* ht_bf   = (__bf16*)(ws + 29738496L);
    __bf16* f1_bf   = (__bf16*)(ws + 32146944L);
    // aliases (time-disjoint within a layer):
    __bf16* o2_bf   = (__bf16*)(ws + 34555392L);
    __bf16* f2_bf   = (__bf16*)(ws + 24921600L);
    __bf16* hadd_bf = (__bf16*)(ws + 28534272L);
    // ---- CA phase ----
    float* tc   = ws;
    __bf16* hc_bf = (__bf16*)(ws + 2420736L);
    __bf16* qkvc_bf = (__bf16*)(ws + 4841472L);
    float* clsp = ws + 8472576L;
    float* clso = clsp + 12288;
    float* f1c  = clso + 12288;
    float* cls2 = f1c + 49152;
    float* clsf = cls2 + 12288;
    __bf16* cqkv_bf  = (__bf16*)(ws + 9000000L);
    __bf16* cproj_bf = (__bf16*)(ws + 9500000L);
    __bf16* cfc1_bf  = (__bf16*)(ws + 9800000L);
    __bf16* cfc2_bf  = (__bf16*)(ws + 10400000L);
    __bf16* headw_bf = (__bf16*)(ws + 11000000L);

    // ---- conv weight prep ----
    wprep<<<(48 * 32 + 255) / 256, 256, 0, stream>>>(pe_w[0], W1c, 48, 3, 32);
    wprep<<<(96 * 448 + 255) / 256, 256, 0, stream>>>(pe_w[1], W2c, 96, 48, 448);
    wprep<<<(192 * 896 + 255) / 256, 256, 0, stream>>>(pe_w[2], W3c, 192, 96, 896);
    wprep<<<(384 * 1728 + 255) / 256, 256, 0, stream>>>(pe_w[3], W4c, 384, 192, 1728);

    // ---- patch embed: conv1 via im2col; conv2/3/4 via implicit-im2col MFMA GEMM ----
    im2col_x<<<1568, 256, 0, stream>>>(x, A1);
    { dim3 g(3136, 1); gemm_conv<1, 0><<<g, 256, 0, stream>>>(A1, 32, W1c, pe_g[0], pe_b[0], out1, 48, nullptr); }
    pos_embed<<<196, 384, 0, stream>>>(pos_w, pos_b, pos);
    { dim3 g(784, 1);
      gemm_cig<1, 0, 48, 112, 112, 56, 56><<<g, 256, 0, stream>>>(out1, 448, W2c, pe_g[1], pe_b[1], out2, 96, nullptr); }
    { dim3 g(196, 2);
      gemm_cig<1, 0, 96, 56, 56, 28, 28><<<g, 256, 0, stream>>>(out2, 896, W3c, pe_g[2], pe_b[2], out3, 192, nullptr); }
    { dim3 g(49, 3);
      gemm_cig<0, 1, 192, 28, 28, 14, 14><<<g, 256, 0, stream>>>(out3, 1728, W4c, pe_g[3], pe_b[3], t, 384, pos); }

    // ---- convert XCA weights to bf16 ----
    {
        long n1 = (long)L_ * 1152 * 384;
        long n2 = (long)L_ * 384 * 384;
        long n3 = (long)L_ * 1536 * 384;
        cvt_bf<<<(int)((n1 + 2047) / 2048), 256, 0, stream>>>(xqkv_w, wqkv_bf, n1);
        cvt_bf<<<(int)((n2 + 2047) / 2048), 256, 0, stream>>>(xproj_w, wproj_bf, n2);
        cvt_bf<<<(int)((n3 + 2047) / 2048), 256, 0, stream>>>(xfc1_w, wfc1_bf, n3);
        cvt_bf<<<(int)((n3 + 2047) / 2048), 256, 0, stream>>>(xfc2_w, wfc2_bf, n3);
    }

    // ---- 24 XCA layers ----
    const int M = B_ * N_;  // 6272 = 49*128
    ln384_bf<<<M, 128, 0, stream>>>(t, xn1_w, xn1_b, h_bf);   // initial LN1
    for (int l = 0; l < L_; l++){
        {   // qkv: 128x128 tile
            dim3 g(49, 9);
            gemm_bb4<0><<<g, 256, 0, stream>>>(h_bf, 384, wqkv_bf + (long)l * 1152 * 384, 384,
                                               xqkv_b + l * 1152, qkv_bf, 1152, 384);
        }
        xca2<<<B_ * NH_, 256, 0, stream>>>(qkv_bf, xtemp + l * 8, o_bf);
        {   // proj: 64x64 tiles
            dim3 g(98, 6);
            gemm_bb3<<<g, 256, 0, stream>>>(o_bf, 384, wproj_bf + (long)l * 384 * 384, 384,
                                            xproj_b + l * 384, o2_bf, 384, 384);
        }
        proj_res_lnt<<<M, 128, 0, stream>>>(o2_bf, xg1 + l * 384, t,
                                            xn3_w + l * 384, xn3_b + l * 384, ht_bf);
        lpi_g<<<B_ * D_, 256, 0, stream>>>(ht_bf, xlpi1_w + (long)l * 384 * 9, xlpi1_b + l * 384,
                                           xbn_g + l * 384, xbn_b + l * 384,
                                           xlpi2_w + (long)l * 384 * 9, xlpi2_b + l * 384,
                                           xg3 + l * 384, hadd_bf);
        ln2res<<<M, 128, 0, stream>>>(t, hadd_bf, xn2_w + l * 384, xn2_b + l * 384, h_bf);
        {   // fc1: 128x128 tile, fused GELU
            dim3 g(49, 12);
            gemm_bb4<1><<<g, 256, 0, stream>>>(h_bf, 384, wfc1_bf + (long)l * 1536 * 384, 384,
                                               xfc1_b + l * 1536, f1_bf, 1536, 384);
        }
        {   // fc2: 64x64 tiles
            dim3 g(98, 6);
            gemm_bb3<<<g, 256, 0, stream>>>(f1_bf, 1536, wfc2_bf + (long)l * 1536 * 384, 1536,
                                            xfc2_b + l * 384, f2_bf, 384, 1536);
        }
        int ln = (l + 1) % L_;
        fc2_res_ln<<<M, 128, 0, stream>>>(f2_bf, xg2 + l * 384, t,
                                          xn1_w + ln * 384, xn1_b + ln * 384, h_bf);
    }

    // ---- cls concat + 2 CA blocks (bf16 hc) ----
    const long NC = (long)B_ * 197 * 384;
    concat_cls<<<(int)(NC / 256), 256, 0, stream>>>(t, clstok, tc);
    {
        long nc = (long)2 * 1152 * 384;
        cvt_bf<<<(int)((nc + 2047) / 2048), 256, 0, stream>>>(cqkv_w, cqkv_bf, nc);
        long np = (long)2 * 384 * 384;
        cvt_bf<<<(int)((np + 2047) / 2048), 256, 0, stream>>>(cproj_w, cproj_bf, np);
        long nf = (long)2 * 1536 * 384;
        cvt_bf<<<(int)((nf + 2047) / 2048), 256, 0, stream>>>(cfc1_w, cfc1_bf, nf);
        cvt_bf<<<(int)((nf + 2047) / 2048), 256, 0, stream>>>(cfc2_w, cfc2_bf, nf);
        cvt_pad<<<(1024 * 384 + 255) / 256, 256, 0, stream>>>(head_w, headw_bf, 1000, 384, 1024);
    }
    const int MC = B_ * 197;  // 6304
    for (int i = 0; i < 2; i++){
        ln384_bf<<<MC, 128, 0, stream>>>(tc, cn1_w + i * 384, cn1_b + i * 384, hc_bf);
        {
            dim3 g(99, 9);
            gemm_bb2<0, 1, 0, 1, 0><<<g, 256, 0, stream>>>(hc_bf, 384, cqkv_bf + (long)i * 1152 * 384, 384,
                                                           cqkv_b + i * 1152, qkvc_bf, 1152, 384, MC, 0);
        }
        ca_attn<<<B_ * NH_, 256, 0, stream>>>(qkvc_bf, clsp);
        {
            dim3 g(1, 3);
            gemm_bb2<0, 0, 1, 1, 0><<<g, 256, 0, stream>>>(clsp, 384, cproj_bf + (long)i * 384 * 384, 384,
                                                           cproj_b + i * 384, clso, 384, 384, 32, 0);
        }
        ca_update1<<<(int)(NC / 256), 256, 0, stream>>>(clso, hc_bf, cg1 + i * 384, tc);
        ln384_bf<<<MC, 128, 0, stream>>>(tc, cn2_w + i * 384, cn2_b + i * 384, hc_bf);
        {
            dim3 g(1, 12);
            gemm_bb2<1, 0, 0, 1, 0><<<g, 256, 0, stream>>>(hc_bf, (long)197 * 384, cfc1_bf + (long)i * 1536 * 384, 384,
                                                           cfc1_b + i * 1536, f1c, 1536, 384, 32, 0);
        }
        {
            dim3 g(1, 3);
            gemm_bb2<0, 0, 1, 1, 0><<<g, 256, 0, stream>>>(f1c, 1536, cfc2_bf + (long)i * 1536 * 384, 1536,
                                                           cfc2_b + i * 384, cls2, 384, 1536, 32, 0);
        }
        ca_update2<<<(int)(NC / 256), 256, 0, stream>>>(cls2, hc_bf, cg2 + i * 384, tc);
    }

    // ---- final LN (cls token only) + head ----
    ln384<<<32, 128, 0, stream>>>(tc, (long)197 * 384, norm_w, norm_b, clsf, 384);
    {
        dim3 g(1, 8);
        gemm_bb2<0, 0, 1, 1, 1><<<g, 256, 0, stream>>>(clsf, 384, headw_bf, 384,
                                                       head_b, outp, 1000, 384, 32, 1000);
    }
}

// Round 14
// 3714.971 us; speedup vs baseline: 1.0612x; 1.0612x over previous
//
#include <hip/hip_runtime.h>
#include <hip/hip_bf16.h>

#define B_ 32
#define D_ 384
#define N_ 196
#define NH_ 8
#define HD_ 48
#define L_ 24

typedef __bf16 bf16x8 __attribute__((ext_vector_type(8)));
typedef __bf16 bf16x4 __attribute__((ext_vector_type(4)));
typedef float f32x4 __attribute__((ext_vector_type(4)));

__device__ __forceinline__ float gelu_f(float v){
    return 0.5f * v * (1.0f + erff(v * 0.70710678118654752f));
}

// ---------------- fp32 -> bf16 bulk convert ----------------
__global__ __launch_bounds__(256) void cvt_bf(const float* __restrict__ s, __bf16* __restrict__ d, long n){
    long i = ((long)blockIdx.x * 256 + threadIdx.x) * 8;
    if (i >= n) return;
    float4 a = *reinterpret_cast<const float4*>(s + i);
    float4 b = *reinterpret_cast<const float4*>(s + i + 4);
    bf16x8 r;
    r[0] = (__bf16)a.x; r[1] = (__bf16)a.y; r[2] = (__bf16)a.z; r[3] = (__bf16)a.w;
    r[4] = (__bf16)b.x; r[5] = (__bf16)b.y; r[6] = (__bf16)b.z; r[7] = (__bf16)b.w;
    *reinterpret_cast<bf16x8*>(d + i) = r;
}

// fp32 -> bf16 with row padding (zero rows >= rows)
__global__ __launch_bounds__(256) void cvt_pad(const float* __restrict__ s, __bf16* __restrict__ d,
                                               int rows, int K, int rows_pad){
    int id = blockIdx.x * 256 + threadIdx.x;
    if (id >= rows_pad * K) return;
    int r = id / K;
    d[id] = (r < rows) ? (__bf16)s[id] : (__bf16)0.f;
}

// ---------------- conv weight reorder: W'[co][tap*Ci+ci] (bf16, K padded) ----------------
__global__ __launch_bounds__(256) void wprep(const float* __restrict__ w, __bf16* __restrict__ W2,
                                             int Co, int Ci, int Kpad){
    int id = blockIdx.x * 256 + threadIdx.x;
    if (id >= Co * Kpad) return;
    int co = id / Kpad, k = id - co * Kpad;
    float v = 0.f;
    if (k < 9 * Ci){
        int tap = k / Ci, ci = k - tap * Ci;
        v = w[((long)co * Ci + ci) * 9 + tap];
    }
    W2[id] = (__bf16)v;
}

// ---------------- im2col for conv1 (fp32 NCHW input) -> A[pix][32] bf16 ----------------
__global__ __launch_bounds__(256) void im2col_x(const float* __restrict__ x, __bf16* __restrict__ A){
    int id = blockIdx.x * 256 + threadIdx.x;
    if (id >= 401408) return;
    int ox = id % 112; int t1 = id / 112; int oy = t1 % 112; int b = t1 / 112;
    __bf16 buf[32];
    #pragma unroll
    for (int i = 0; i < 32; i++) buf[i] = (__bf16)0.f;
    const float* xb = x + (long)b * 3 * 224 * 224;
    #pragma unroll
    for (int tap = 0; tap < 9; tap++){
        int ky = tap / 3, kx = tap % 3;
        int iy = oy * 2 - 1 + ky, ix = ox * 2 - 1 + kx;
        if ((unsigned)iy < 224u && (unsigned)ix < 224u){
            #pragma unroll
            for (int ci = 0; ci < 3; ci++)
                buf[tap * 3 + ci] = (__bf16)xb[((long)ci * 224 + iy) * 224 + ix];
        }
    }
    __bf16* dst = A + (long)id * 32;
    #pragma unroll
    for (int i = 0; i < 4; i++)
        *reinterpret_cast<bf16x8*>(dst + i * 8) = *reinterpret_cast<bf16x8*>(buf + i * 8);
}

// ---------------- conv GEMM for conv1: 128x128 tile, BK=32, fused BN+GELU ----------------
template<int GELU, int POSOUT>
__global__ __launch_bounds__(256) void gemm_conv(const __bf16* __restrict__ A, int Kpad,
                                                 const __bf16* __restrict__ W,
                                                 const float* __restrict__ g, const float* __restrict__ bb,
                                                 void* __restrict__ Cv, int N,
                                                 const float* __restrict__ pos){
    __shared__ __align__(16) char smem[20480];
    char* Ab = smem;
    char* Bb = smem + 10240;
    const int tid  = threadIdx.x;
    const int lane = tid & 63;
    const int wn   = (tid >> 6) & 1;
    const int wm   = tid >> 7;
    const int row0 = blockIdx.x * 128;
    const int col0 = blockIdx.y * 128;
    const int hi = lane >> 4, lo = lane & 15;
    f32x4 acc[4][4] = {};
    auto loadA = [&](int kk, int i)->bf16x8 {
        int p = i * 256 + tid;
        int r = p >> 2, cq = p & 3;
        return *reinterpret_cast<const bf16x8*>(A + (long)(row0 + r) * Kpad + kk + cq * 8);
    };
    auto loadB = [&](int kk, int i)->bf16x8 {
        int p = i * 256 + tid;
        int r = p >> 2, cq = p & 3;
        int gc = col0 + r;
        bf16x8 vw{};
        if (gc < N) vw = *reinterpret_cast<const bf16x8*>(W + (long)gc * Kpad + kk + cq * 8);
        return vw;
    };
    bf16x8 vaC0 = loadA(0, 0), vaC1 = loadA(0, 1);
    bf16x8 vwC0 = loadB(0, 0), vwC1 = loadB(0, 1);
    for (int k0 = 0; k0 < Kpad; k0 += 32){
        #pragma unroll
        for (int i = 0; i < 2; i++){
            int p = i * 256 + tid;
            int r = p >> 2, cq = p & 3;
            *reinterpret_cast<bf16x8*>(Ab + r * 80 + cq * 16) = i ? vaC1 : vaC0;
            *reinterpret_cast<bf16x8*>(Bb + r * 80 + cq * 16) = i ? vwC1 : vwC0;
        }
        __syncthreads();
        int kn = (k0 + 32 < Kpad) ? k0 + 32 : k0;
        bf16x8 vaN0 = loadA(kn, 0), vaN1 = loadA(kn, 1);
        bf16x8 vwN0 = loadB(kn, 0), vwN1 = loadB(kn, 1);
        bf16x8 af[4], bfr[4];
        #pragma unroll
        for (int m = 0; m < 4; m++)
            af[m] = *reinterpret_cast<const bf16x8*>(Ab + (wm * 64 + m * 16 + lo) * 80 + hi * 16);
        #pragma unroll
        for (int n = 0; n < 4; n++)
            bfr[n] = *reinterpret_cast<const bf16x8*>(Bb + (wn * 64 + n * 16 + lo) * 80 + hi * 16);
        #pragma unroll
        for (int m = 0; m < 4; m++)
            #pragma unroll
            for (int n = 0; n < 4; n++)
                acc[m][n] = __builtin_amdgcn_mfma_f32_16x16x32_bf16(af[m], bfr[n], acc[m][n], 0, 0, 0);
        __syncthreads();
        vaC0 = vaN0; vaC1 = vaN1; vwC0 = vwN0; vwC1 = vwN1;
    }
    float* Cf = (float*)Cv;
    __bf16* Cb = (__bf16*)Cv;
    #pragma unroll
    for (int m = 0; m < 4; m++){
        #pragma unroll
        for (int n = 0; n < 4; n++){
            int row = row0 + wm * 64 + m * 16 + hi * 4;
            int col = col0 + wn * 64 + n * 16 + lo;
            if (col >= N) continue;
            float scale = g[col] * rsqrtf(1.0f + 1e-5f);
            float bv = bb[col];
            #pragma unroll
            for (int j = 0; j < 4; j++){
                float v = acc[m][n][j] * scale + bv;
                if (GELU) v = gelu_f(v);
                if (POSOUT)
                    Cf[(long)(row + j) * 384 + col] = v + pos[((row + j) % 196) * 384 + col];
                else
                    Cb[(long)(row + j) * N + col] = (__bf16)v;
            }
        }
    }
}

// ---------------- implicit-im2col conv GEMM (conv2/3/4): gathers A from [pix][C] bf16 ----------------
template<int GELU, int POSOUT, int C, int Hi, int Wi, int Ho, int Wo>
__global__ __launch_bounds__(256) void gemm_cig(const __bf16* __restrict__ in, int Kpad,
                                                const __bf16* __restrict__ W,
                                                const float* __restrict__ g, const float* __restrict__ bb,
                                                void* __restrict__ Cv, int N,
                                                const float* __restrict__ pos){
    __shared__ __align__(16) char smem[36864];
    char* Ab = smem;
    char* Bb = smem + 18432;
    const int tid  = threadIdx.x;
    const int lane = tid & 63;
    const int wn   = (tid >> 6) & 1;
    const int wm   = tid >> 7;
    const int row0 = blockIdx.x * 128;
    const int col0 = blockIdx.y * 128;
    const int hi = lane >> 4, lo = lane & 15;
    f32x4 acc[4][4] = {};
    auto loadA = [&](int kk, int i)->bf16x8 {
        int p = i * 256 + tid;
        int r = p >> 3, cq = p & 7;
        int koff = kk + cq * 8;
        int tap = koff / C;
        int ci = koff - tap * C;
        bf16x8 va{};
        if (tap < 9){
            int pix = row0 + r;
            int b = pix / (Ho * Wo);
            int rem = pix - b * (Ho * Wo);
            int oy = rem / Wo, ox = rem - oy * Wo;
            int iy = oy * 2 - 1 + tap / 3, ix = ox * 2 - 1 + tap % 3;
            if ((unsigned)iy < (unsigned)Hi && (unsigned)ix < (unsigned)Wi)
                va = *reinterpret_cast<const bf16x8*>(in + (((long)b * Hi + iy) * Wi + ix) * C + ci);
        }
        return va;
    };
    auto loadB = [&](int kk, int i)->bf16x8 {
        int p = i * 256 + tid;
        int r = p >> 3, cq = p & 7;
        int gc = col0 + r;
        bf16x8 vw{};
        if (gc < N) vw = *reinterpret_cast<const bf16x8*>(W + (long)gc * Kpad + kk + cq * 8);
        return vw;
    };
    bf16x8 vaC[4], vwC[4];
    #pragma unroll
    for (int i = 0; i < 4; i++){ vaC[i] = loadA(0, i); vwC[i] = loadB(0, i); }
    for (int k0 = 0; k0 < Kpad; k0 += 64){
        #pragma unroll
        for (int i = 0; i < 4; i++){
            int p = i * 256 + tid;
            int r = p >> 3, cq = p & 7;
            *reinterpret_cast<bf16x8*>(Ab + r * 144 + cq * 16) = vaC[i];
            *reinterpret_cast<bf16x8*>(Bb + r * 144 + cq * 16) = vwC[i];
        }
        __syncthreads();
        int kn = (k0 + 64 < Kpad) ? k0 + 64 : k0;
        bf16x8 vaN[4], vwN[4];
        #pragma unroll
        for (int i = 0; i < 4; i++){ vaN[i] = loadA(kn, i); vwN[i] = loadB(kn, i); }
        bf16x8 af[2][4], bfr[2][4];
        #pragma unroll
        for (int m = 0; m < 4; m++){
            af[0][m] = *reinterpret_cast<const bf16x8*>(Ab + (wm * 64 + m * 16 + lo) * 144 + hi * 16);
            af[1][m] = *reinterpret_cast<const bf16x8*>(Ab + (wm * 64 + m * 16 + lo) * 144 + 64 + hi * 16);
        }
        #pragma unroll
        for (int n = 0; n < 4; n++){
            bfr[0][n] = *reinterpret_cast<const bf16x8*>(Bb + (wn * 64 + n * 16 + lo) * 144 + hi * 16);
            bfr[1][n] = *reinterpret_cast<const bf16x8*>(Bb + (wn * 64 + n * 16 + lo) * 144 + 64 + hi * 16);
        }
        #pragma unroll
        for (int kc = 0; kc < 2; kc++)
            #pragma unroll
            for (int m = 0; m < 4; m++)
                #pragma unroll
                for (int n = 0; n < 4; n++)
                    acc[m][n] = __builtin_amdgcn_mfma_f32_16x16x32_bf16(af[kc][m], bfr[kc][n], acc[m][n], 0, 0, 0);
        __syncthreads();
        #pragma unroll
        for (int i = 0; i < 4; i++){ vaC[i] = vaN[i]; vwC[i] = vwN[i]; }
    }
    float* Cf = (float*)Cv;
    __bf16* Cb = (__bf16*)Cv;
    #pragma unroll
    for (int m = 0; m < 4; m++){
        #pragma unroll
        for (int n = 0; n < 4; n++){
            int row = row0 + wm * 64 + m * 16 + hi * 4;
            int col = col0 + wn * 64 + n * 16 + lo;
            if (col >= N) continue;
            float scale = g[col] * rsqrtf(1.0f + 1e-5f);
            float bv = bb[col];
            #pragma unroll
            for (int j = 0; j < 4; j++){
                float v = acc[m][n][j] * scale + bv;
                if (GELU) v = gelu_f(v);
                if (POSOUT)
                    Cf[(long)(row + j) * 384 + col] = v + pos[((row + j) % 196) * 384 + col];
                else
                    Cb[(long)(row + j) * N + col] = (__bf16)v;
            }
        }
    }
}

// ---------------- LayerNorm over D=384, fp32 out ----------------
__global__ __launch_bounds__(128) void ln384(const float* __restrict__ x, long xstride,
                                             const float* __restrict__ w, const float* __restrict__ b,
                                             float* __restrict__ y, long ystride){
    long row = blockIdx.x;
    int tid = threadIdx.x;
    const float* xr = x + row * xstride;
    float v0 = xr[tid], v1 = xr[tid + 128], v2 = xr[tid + 256];
    float s = v0 + v1 + v2;
    float ss = v0 * v0 + v1 * v1 + v2 * v2;
    for (int off = 32; off; off >>= 1){ s += __shfl_down(s, off); ss += __shfl_down(ss, off); }
    __shared__ float rs[2], rss[2];
    if ((tid & 63) == 0){ rs[tid >> 6] = s; rss[tid >> 6] = ss; }
    __syncthreads();
    float S = rs[0] + rs[1], SS = rss[0] + rss[1];
    float m = S * (1.0f / 384.0f);
    float var = SS * (1.0f / 384.0f) - m * m;
    float r = rsqrtf(var + 1e-5f);
    float* yr = y + row * ystride;
    yr[tid]       = (v0 - m) * r * w[tid]       + b[tid];
    yr[tid + 128] = (v1 - m) * r * w[tid + 128] + b[tid + 128];
    yr[tid + 256] = (v2 - m) * r * w[tid + 256] + b[tid + 256];
}

// ---------------- LayerNorm, bf16 out (row stride 384) ----------------
__global__ __launch_bounds__(128) void ln384_bf(const float* __restrict__ x,
                                                const float* __restrict__ w, const float* __restrict__ b,
                                                __bf16* __restrict__ y){
    long row = blockIdx.x;
    int tid = threadIdx.x;
    const float* xr = x + row * 384;
    float v0 = xr[tid], v1 = xr[tid + 128], v2 = xr[tid + 256];
    float s = v0 + v1 + v2;
    float ss = v0 * v0 + v1 * v1 + v2 * v2;
    for (int off = 32; off; off >>= 1){ s += __shfl_down(s, off); ss += __shfl_down(ss, off); }
    __shared__ float rs[2], rss[2];
    if ((tid & 63) == 0){ rs[tid >> 6] = s; rss[tid >> 6] = ss; }
    __syncthreads();
    float S = rs[0] + rs[1], SS = rss[0] + rss[1];
    float m = S * (1.0f / 384.0f);
    float var = SS * (1.0f / 384.0f) - m * m;
    float r = rsqrtf(var + 1e-5f);
    __bf16* yr = y + row * 384;
    yr[tid]       = (__bf16)((v0 - m) * r * w[tid]       + b[tid]);
    yr[tid + 128] = (__bf16)((v1 - m) * r * w[tid + 128] + b[tid + 128]);
    yr[tid + 256] = (__bf16)((v2 - m) * r * w[tid + 256] + b[tid + 256]);
}

// ---------------- t += g1*o2 ; ht = LN3(t) transposed (bf16) ----------------
__global__ __launch_bounds__(128) void proj_res_lnt(const __bf16* __restrict__ o2,
                                                    const float* __restrict__ g1,
                                                    float* __restrict__ t,
                                                    const float* __restrict__ n3w, const float* __restrict__ n3b,
                                                    __bf16* __restrict__ ht){
    long row = blockIdx.x;
    int tid = threadIdx.x;
    int c0 = tid * 4;
    float v[4] = {0.f, 0.f, 0.f, 0.f};
    if (tid < 96){
        float4 tv = *reinterpret_cast<const float4*>(t + row * 384 + c0);
        bf16x4 ov = *reinterpret_cast<const bf16x4*>(o2 + row * 384 + c0);
        v[0] = tv.x + g1[c0 + 0] * (float)ov[0];
        v[1] = tv.y + g1[c0 + 1] * (float)ov[1];
        v[2] = tv.z + g1[c0 + 2] * (float)ov[2];
        v[3] = tv.w + g1[c0 + 3] * (float)ov[3];
        *reinterpret_cast<float4*>(t + row * 384 + c0) = make_float4(v[0], v[1], v[2], v[3]);
    }
    float s = v[0] + v[1] + v[2] + v[3];
    float ss = v[0] * v[0] + v[1] * v[1] + v[2] * v[2] + v[3] * v[3];
    for (int off = 32; off; off >>= 1){ s += __shfl_down(s, off); ss += __shfl_down(ss, off); }
    __shared__ float rs[2], rss[2];
    if ((tid & 63) == 0){ rs[tid >> 6] = s; rss[tid >> 6] = ss; }
    __syncthreads();
    float S = rs[0] + rs[1], SS = rss[0] + rss[1];
    float m = S * (1.0f / 384.0f);
    float var = SS * (1.0f / 384.0f) - m * m;
    float r = rsqrtf(var + 1e-5f);
    if (tid < 96){
        int b = (int)(row / 196), n = (int)(row % 196);
        __bf16* yb = ht + ((long)b * 384) * 196 + n;
        #pragma unroll
        for (int j = 0; j < 4; j++){
            int c = c0 + j;
            yb[(long)c * 196] = (__bf16)((v[j] - m) * r * n3w[c] + n3b[c]);
        }
    }
}

// ---------------- t += hadd ; h = LN2(t) bf16 ----------------
__global__ __launch_bounds__(128) void ln2res(float* __restrict__ t,
                                              const __bf16* __restrict__ hadd,
                                              const float* __restrict__ n2w, const float* __restrict__ n2b,
                                              __bf16* __restrict__ h){
    long row = blockIdx.x;
    int tid = threadIdx.x;
    int c0 = tid * 4;
    float v[4] = {0.f, 0.f, 0.f, 0.f};
    if (tid < 96){
        float4 tv = *reinterpret_cast<const float4*>(t + row * 384 + c0);
        bf16x4 hv = *reinterpret_cast<const bf16x4*>(hadd + row * 384 + c0);
        v[0] = tv.x + (float)hv[0];
        v[1] = tv.y + (float)hv[1];
        v[2] = tv.z + (float)hv[2];
        v[3] = tv.w + (float)hv[3];
        *reinterpret_cast<float4*>(t + row * 384 + c0) = make_float4(v[0], v[1], v[2], v[3]);
    }
    float s = v[0] + v[1] + v[2] + v[3];
    float ss = v[0] * v[0] + v[1] * v[1] + v[2] * v[2] + v[3] * v[3];
    for (int off = 32; off; off >>= 1){ s += __shfl_down(s, off); ss += __shfl_down(ss, off); }
    __shared__ float rs[2], rss[2];
    if ((tid & 63) == 0){ rs[tid >> 6] = s; rss[tid >> 6] = ss; }
    __syncthreads();
    float S = rs[0] + rs[1], SS = rss[0] + rss[1];
    float m = S * (1.0f / 384.0f);
    float var = SS * (1.0f / 384.0f) - m * m;
    float r = rsqrtf(var + 1e-5f);
    if (tid < 96){
        bf16x4 o;
        #pragma unroll
        for (int j = 0; j < 4; j++){
            int c = c0 + j;
            o[j] = (__bf16)((v[j] - m) * r * n2w[c] + n2b[c]);
        }
        *reinterpret_cast<bf16x4*>(h + row * 384 + c0) = o;
    }
}

// ---------------- t += g2*f2 ; h = LN1next(t) bf16 ----------------
__global__ __launch_bounds__(128) void fc2_res_ln(const __bf16* __restrict__ f2,
                                                  const float* __restrict__ g2,
                                                  float* __restrict__ t,
                                                  const float* __restrict__ n1w, const float* __restrict__ n1b,
                                                  __bf16* __restrict__ h){
    long row = blockIdx.x;
    int tid = threadIdx.x;
    int c0 = tid * 4;
    float v[4] = {0.f, 0.f, 0.f, 0.f};
    if (tid < 96){
        float4 tv = *reinterpret_cast<const float4*>(t + row * 384 + c0);
        bf16x4 fv = *reinterpret_cast<const bf16x4*>(f2 + row * 384 + c0);
        v[0] = tv.x + g2[c0 + 0] * (float)fv[0];
        v[1] = tv.y + g2[c0 + 1] * (float)fv[1];
        v[2] = tv.z + g2[c0 + 2] * (float)fv[2];
        v[3] = tv.w + g2[c0 + 3] * (float)fv[3];
        *reinterpret_cast<float4*>(t + row * 384 + c0) = make_float4(v[0], v[1], v[2], v[3]);
    }
    float s = v[0] + v[1] + v[2] + v[3];
    float ss = v[0] * v[0] + v[1] * v[1] + v[2] * v[2] + v[3] * v[3];
    for (int off = 32; off; off >>= 1){ s += __shfl_down(s, off); ss += __shfl_down(ss, off); }
    __shared__ float rs[2], rss[2];
    if ((tid & 63) == 0){ rs[tid >> 6] = s; rss[tid >> 6] = ss; }
    __syncthreads();
    float S = rs[0] + rs[1], SS = rss[0] + rss[1];
    float m = S * (1.0f / 384.0f);
    float var = SS * (1.0f / 384.0f) - m * m;
    float r = rsqrtf(var + 1e-5f);
    if (tid < 96){
        bf16x4 o;
        #pragma unroll
        for (int j = 0; j < 4; j++){
            int c = c0 + j;
            o[j] = (__bf16)((v[j] - m) * r * n1w[c] + n1b[c]);
        }
        *reinterpret_cast<bf16x4*>(h + row * 384 + c0) = o;
    }
}

// ---------------- bf16 MFMA GEMM, 64x128 tile, 4 waves, BK=64, 2-stage prefetch ----------------
template<int MODE, int OUTBF, int ACVT, int GUARD, int NGUARD>
__global__ __launch_bounds__(256) void gemm_bb2(const void* __restrict__ Av, long lda,
                                                const __bf16* __restrict__ W, int Kw,
                                                const float* __restrict__ bias,
                                                void* __restrict__ Cv, long ldc,
                                                int K, int M, int Ncols){
    __shared__ __align__(16) char smem[27648];
    char* Ab = smem;            // 64 rows x 144B
    char* Bb = smem + 9216;     // 128 rows x 144B
    const int tid = threadIdx.x;
    const int lane = tid & 63;
    const int wn = tid >> 6;
    const int row0 = blockIdx.x * 64;
    const int col0 = blockIdx.y * 128;
    const int hi = lane >> 4, lo = lane & 15;
    const __bf16* Abf = (const __bf16*)Av;
    const float* Af = (const float*)Av;
    f32x4 acc[4][2] = {};
    auto loadA = [&](int kk, int i)->bf16x8 {
        int p = i * 256 + tid;
        int r = p >> 3, cq = p & 7;
        bf16x8 va{};
        int grow = row0 + r;
        if (!GUARD || grow < M){
            long ai = (long)grow * lda + kk + cq * 8;
            if (ACVT){
                float4 a0 = *reinterpret_cast<const float4*>(Af + ai);
                float4 a1 = *reinterpret_cast<const float4*>(Af + ai + 4);
                va[0] = (__bf16)a0.x; va[1] = (__bf16)a0.y; va[2] = (__bf16)a0.z; va[3] = (__bf16)a0.w;
                va[4] = (__bf16)a1.x; va[5] = (__bf16)a1.y; va[6] = (__bf16)a1.z; va[7] = (__bf16)a1.w;
            } else {
                va = *reinterpret_cast<const bf16x8*>(Abf + ai);
            }
        }
        return va;
    };
    auto loadB = [&](int kk, int i)->bf16x8 {
        int p = i * 256 + tid;
        int r = p >> 3, cq = p & 7;
        return *reinterpret_cast<const bf16x8*>(W + (long)(col0 + r) * Kw + kk + cq * 8);
    };
    bf16x8 vaC[2], vwC[4];
    vaC[0] = loadA(0, 0); vaC[1] = loadA(0, 1);
    #pragma unroll
    for (int i = 0; i < 4; i++) vwC[i] = loadB(0, i);
    for (int k0 = 0; k0 < K; k0 += 64){
        #pragma unroll
        for (int i = 0; i < 2; i++){
            int p = i * 256 + tid;
            int r = p >> 3, cq = p & 7;
            *reinterpret_cast<bf16x8*>(Ab + r * 144 + cq * 16) = vaC[i];
        }
        #pragma unroll
        for (int i = 0; i < 4; i++){
            int p = i * 256 + tid;
            int r = p >> 3, cq = p & 7;
            *reinterpret_cast<bf16x8*>(Bb + r * 144 + cq * 16) = vwC[i];
        }
        __syncthreads();
        int kn = (k0 + 64 < K) ? k0 + 64 : k0;
        bf16x8 vaN[2], vwN[4];
        vaN[0] = loadA(kn, 0); vaN[1] = loadA(kn, 1);
        #pragma unroll
        for (int i = 0; i < 4; i++) vwN[i] = loadB(kn, i);
        bf16x8 af[2][4], bfr[2][2];
        #pragma unroll
        for (int m = 0; m < 4; m++){
            af[0][m] = *reinterpret_cast<const bf16x8*>(Ab + (m * 16 + lo) * 144 + hi * 16);
            af[1][m] = *reinterpret_cast<const bf16x8*>(Ab + (m * 16 + lo) * 144 + 64 + hi * 16);
        }
        #pragma unroll
        for (int n = 0; n < 2; n++){
            bfr[0][n] = *reinterpret_cast<const bf16x8*>(Bb + (wn * 32 + n * 16 + lo) * 144 + hi * 16);
            bfr[1][n] = *reinterpret_cast<const bf16x8*>(Bb + (wn * 32 + n * 16 + lo) * 144 + 64 + hi * 16);
        }
        #pragma unroll
        for (int kc = 0; kc < 2; kc++)
            #pragma unroll
            for (int m = 0; m < 4; m++)
                #pragma unroll
                for (int n = 0; n < 2; n++)
                    acc[m][n] = __builtin_amdgcn_mfma_f32_16x16x32_bf16(af[kc][m], bfr[kc][n], acc[m][n], 0, 0, 0);
        __syncthreads();
        vaC[0] = vaN[0]; vaC[1] = vaN[1];
        #pragma unroll
        for (int i = 0; i < 4; i++) vwC[i] = vwN[i];
    }
    float* Cf = (float*)Cv;
    __bf16* Cb = (__bf16*)Cv;
    #pragma unroll
    for (int m = 0; m < 4; m++){
        #pragma unroll
        for (int n = 0; n < 2; n++){
            int row = row0 + m * 16 + hi * 4;
            int col = col0 + wn * 32 + n * 16 + lo;
            if (NGUARD && col >= Ncols) continue;
            float bv = bias[col];
            #pragma unroll
            for (int j = 0; j < 4; j++){
                if (GUARD && (row + j) >= M) continue;
                float v = acc[m][n][j] + bv;
                if (MODE == 1) v = gelu_f(v);
                long ci = (long)(row + j) * ldc + col;
                if (OUTBF) Cb[ci] = (__bf16)v;
                else Cf[ci] = v;
            }
        }
    }
}

// ---------------- bf16 MFMA GEMM, 64x64 tile, 2x2 waves (32x32/wave), BK=64, bf16 out ----------------
__global__ __launch_bounds__(256) void gemm_bb3(const __bf16* __restrict__ A, long lda,
                                                const __bf16* __restrict__ W, int Kw,
                                                const float* __restrict__ bias,
                                                __bf16* __restrict__ C, long ldc,
                                                int K){
    __shared__ __align__(16) char smem[18432];
    char* Ab = smem;            // 64 rows x 144B
    char* Bb = smem + 9216;     // 64 rows x 144B
    const int tid = threadIdx.x;
    const int lane = tid & 63;
    const int wid = tid >> 6;
    const int wm = wid >> 1, wnn = wid & 1;
    const int row0 = blockIdx.x * 64;
    const int col0 = blockIdx.y * 64;
    const int hi = lane >> 4, lo = lane & 15;
    f32x4 acc[2][2] = {};
    auto loadA = [&](int kk, int i)->bf16x8 {
        int p = i * 256 + tid;
        int r = p >> 3, cq = p & 7;
        return *reinterpret_cast<const bf16x8*>(A + (long)(row0 + r) * lda + kk + cq * 8);
    };
    auto loadB = [&](int kk, int i)->bf16x8 {
        int p = i * 256 + tid;
        int r = p >> 3, cq = p & 7;
        return *reinterpret_cast<const bf16x8*>(W + (long)(col0 + r) * Kw + kk + cq * 8);
    };
    bf16x8 vaC[2], vwC[2];
    vaC[0] = loadA(0, 0); vaC[1] = loadA(0, 1);
    vwC[0] = loadB(0, 0); vwC[1] = loadB(0, 1);
    for (int k0 = 0; k0 < K; k0 += 64){
        #pragma unroll
        for (int i = 0; i < 2; i++){
            int p = i * 256 + tid;
            int r = p >> 3, cq = p & 7;
            *reinterpret_cast<bf16x8*>(Ab + r * 144 + cq * 16) = vaC[i];
            *reinterpret_cast<bf16x8*>(Bb + r * 144 + cq * 16) = vwC[i];
        }
        __syncthreads();
        int kn = (k0 + 64 < K) ? k0 + 64 : k0;
        bf16x8 vaN[2], vwN[2];
        vaN[0] = loadA(kn, 0); vaN[1] = loadA(kn, 1);
        vwN[0] = loadB(kn, 0); vwN[1] = loadB(kn, 1);
        bf16x8 af[2][2], bfr[2][2];
        #pragma unroll
        for (int m = 0; m < 2; m++){
            af[0][m] = *reinterpret_cast<const bf16x8*>(Ab + (wm * 32 + m * 16 + lo) * 144 + hi * 16);
            af[1][m] = *reinterpret_cast<const bf16x8*>(Ab + (wm * 32 + m * 16 + lo) * 144 + 64 + hi * 16);
        }
        #pragma unroll
        for (int n = 0; n < 2; n++){
            bfr[0][n] = *reinterpret_cast<const bf16x8*>(Bb + (wnn * 32 + n * 16 + lo) * 144 + hi * 16);
            bfr[1][n] = *reinterpret_cast<const bf16x8*>(Bb + (wnn * 32 + n * 16 + lo) * 144 + 64 + hi * 16);
        }
        #pragma unroll
        for (int kc = 0; kc < 2; kc++)
            #pragma unroll
            for (int m = 0; m < 2; m++)
                #pragma unroll
                for (int n = 0; n < 2; n++)
                    acc[m][n] = __builtin_amdgcn_mfma_f32_16x16x32_bf16(af[kc][m], bfr[kc][n], acc[m][n], 0, 0, 0);
        __syncthreads();
        vaC[0] = vaN[0]; vaC[1] = vaN[1]; vwC[0] = vwN[0]; vwC[1] = vwN[1];
    }
    #pragma unroll
    for (int m = 0; m < 2; m++){
        #pragma unroll
        for (int n = 0; n < 2; n++){
            int row = row0 + wm * 32 + m * 16 + hi * 4;
            int col = col0 + wnn * 32 + n * 16 + lo;
            float bv = bias[col];
            #pragma unroll
            for (int j = 0; j < 4; j++)
                C[(long)(row + j) * ldc + col] = (__bf16)(acc[m][n][j] + bv);
        }
    }
}

// ---------------- positional embedding: pos[n, d] ----------------
__global__ __launch_bounds__(384) void pos_embed(const float* __restrict__ pw, const float* __restrict__ pb,
                                                 float* __restrict__ pos){
    __shared__ float p64[64];
    int n = blockIdx.x;
    int iy = n / 14, ix = n % 14;
    int t = threadIdx.x;
    if (t < 64){
        int axis = t >> 5;
        int c = t & 31;
        int u = c >> 1;
        float coord = (axis == 0) ? (float)(iy + 1) : (float)(ix + 1);
        float val = coord / ((14.0f + 1e-6f) * 6.283185307179586f);
        float T = powf(10000.0f, (float)u / 16.0f);
        float a = val / T;
        p64[t] = (c & 1) ? cosf(a) : sinf(a);
    }
    __syncthreads();
    float acc = 0.f;
    const float* wr = pw + (long)t * 64;
    #pragma unroll 8
    for (int c = 0; c < 64; c++) acc += p64[c] * wr[c];
    pos[n * 384 + t] = acc + pb[t];
}

// ---------------- XCA attention via MFMA: one block per (b, head); V read from global ----------------
__global__ __launch_bounds__(256) void xca2(const __bf16* __restrict__ qkv, const float* __restrict__ temp,
                                            __bf16* __restrict__ o){
    __shared__ __align__(16) char smem[45056];
    __bf16* qs = (__bf16*)smem;                 // 48*232*2 = 22272
    __bf16* ks = (__bf16*)(smem + 22272);       // 22272
    float* inq = (float*)(smem + 44544);        // 192
    float* ink = (float*)(smem + 44736);        // 192
    float* att = (float*)smem;                  // overlay on qs (13056B)
    __bf16* abf = (__bf16*)(smem + 22272);      // overlay on ks (6912B)
    int bh = blockIdx.x;
    int b = bh >> 3, h = bh & 7;
    const int tid = threadIdx.x;
    const int wid = tid >> 6, lane = tid & 63;
    const int hi = lane >> 4, lo = lane & 15;
    const __bf16* base = qkv + ((long)b * 196) * 1152 + h * 48;
    bf16x8 z8 = {};
    for (int idx = tid; idx < 48 * 28; idx += 256){
        int d = idx / 28, n = 196 + idx % 28;
        qs[d * 232 + n] = (__bf16)0.f;
        ks[d * 232 + n] = (__bf16)0.f;
    }
    for (int ch = tid; ch < 196 * 6; ch += 256){
        int n = ch / 6, c = ch % 6, d0 = c * 8;
        bf16x8 q8 = *reinterpret_cast<const bf16x8*>(base + (long)n * 1152 + d0);
        bf16x8 k8 = *reinterpret_cast<const bf16x8*>(base + (long)n * 1152 + 384 + d0);
        #pragma unroll
        for (int j = 0; j < 8; j++){
            qs[(d0 + j) * 232 + n] = q8[j];
            ks[(d0 + j) * 232 + n] = k8[j];
        }
    }
    __syncthreads();
    // row norms: vectorized bf16x4 LDS reads (cols 196..223 are zero)
    for (int r = wid; r < 48; r += 4){
        float sq = 0.f, sk = 0.f;
        if (lane < 56){
            bf16x4 q4 = *reinterpret_cast<const bf16x4*>(qs + r * 232 + lane * 4);
            bf16x4 k4 = *reinterpret_cast<const bf16x4*>(ks + r * 232 + lane * 4);
            #pragma unroll
            for (int j = 0; j < 4; j++){
                float qv = (float)q4[j], kv = (float)k4[j];
                sq += qv * qv; sk += kv * kv;
            }
        }
        for (int off = 32; off; off >>= 1){ sq += __shfl_down(sq, off); sk += __shfl_down(sk, off); }
        if (lane == 0){
            inq[r] = 1.0f / fmaxf(sqrtf(sq), 1e-12f);
            ink[r] = 1.0f / fmaxf(sqrtf(sk), 1e-12f);
        }
    }
    __syncthreads();
    float tempv = temp[h];
    f32x4 qk0 = {}, qk1 = {}, qk2 = {};
    __builtin_amdgcn_s_setprio(1);
    {
        int mi = wid / 3, ni = wid % 3;
        #pragma unroll
        for (int k0 = 0; k0 < 224; k0 += 32){
            bf16x8 af = *reinterpret_cast<const bf16x8*>(qs + (mi * 16 + lo) * 232 + k0 + hi * 8);
            bf16x8 bf = *reinterpret_cast<const bf16x8*>(ks + (ni * 16 + lo) * 232 + k0 + hi * 8);
            qk0 = __builtin_amdgcn_mfma_f32_16x16x32_bf16(af, bf, qk0, 0, 0, 0);
        }
    }
    {
        int tt = wid + 4;
        int mi = tt / 3, ni = tt % 3;
        #pragma unroll
        for (int k0 = 0; k0 < 224; k0 += 32){
            bf16x8 af = *reinterpret_cast<const bf16x8*>(qs + (mi * 16 + lo) * 232 + k0 + hi * 8);
            bf16x8 bf = *reinterpret_cast<const bf16x8*>(ks + (ni * 16 + lo) * 232 + k0 + hi * 8);
            qk1 = __builtin_amdgcn_mfma_f32_16x16x32_bf16(af, bf, qk1, 0, 0, 0);
        }
    }
    if (wid == 0){
        #pragma unroll
        for (int k0 = 0; k0 < 224; k0 += 32){
            bf16x8 af = *reinterpret_cast<const bf16x8*>(qs + (2 * 16 + lo) * 232 + k0 + hi * 8);
            bf16x8 bf = *reinterpret_cast<const bf16x8*>(ks + (2 * 16 + lo) * 232 + k0 + hi * 8);
            qk2 = __builtin_amdgcn_mfma_f32_16x16x32_bf16(af, bf, qk2, 0, 0, 0);
        }
    }
    __builtin_amdgcn_s_setprio(0);
    __syncthreads();   // qs/ks reads done; overlays writable
    {
        int mi = wid / 3, ni = wid % 3;
        int e = ni * 16 + lo;
        float se = ink[e] * tempv;
        #pragma unroll
        for (int j = 0; j < 4; j++){
            int d = mi * 16 + hi * 4 + j;
            att[d * 68 + e] = qk0[j] * inq[d] * se;
        }
    }
    {
        int tt = wid + 4;
        int mi = tt / 3, ni = tt % 3;
        int e = ni * 16 + lo;
        float se = ink[e] * tempv;
        #pragma unroll
        for (int j = 0; j < 4; j++){
            int d = mi * 16 + hi * 4 + j;
            att[d * 68 + e] = qk1[j] * inq[d] * se;
        }
    }
    if (wid == 0){
        int e = 2 * 16 + lo;
        float se = ink[e] * tempv;
        #pragma unroll
        for (int j = 0; j < 4; j++){
            int d = 2 * 16 + hi * 4 + j;
            att[d * 68 + e] = qk2[j] * inq[d] * se;
        }
    }
    __syncthreads();
    if (tid < 192){
        int r = tid >> 2, q4 = tid & 3;
        const float* row = att + r * 68 + q4 * 12;
        float mx = -1e30f;
        #pragma unroll
        for (int i = 0; i < 12; i++) mx = fmaxf(mx, row[i]);
        mx = fmaxf(mx, __shfl_xor(mx, 1));
        mx = fmaxf(mx, __shfl_xor(mx, 2));
        float pv[12]; float sm = 0.f;
        #pragma unroll
        for (int i = 0; i < 12; i++){ pv[i] = expf(row[i] - mx); sm += pv[i]; }
        sm += __shfl_xor(sm, 1);
        sm += __shfl_xor(sm, 2);
        float inv = 1.0f / sm;
        #pragma unroll
        for (int i = 0; i < 12; i++) abf[r * 72 + q4 * 12 + i] = (__bf16)(pv[i] * inv);
    }
    for (int idx = tid; idx < 48 * 3; idx += 256){
        int r = idx / 3, c = 48 + (idx % 3) * 8;
        *reinterpret_cast<bf16x8*>(abf + r * 72 + c) = z8;
    }
    __syncthreads();
    // PV: A = abf (LDS), B = V from global (qkv[n][768+e], contiguous in e).
    __bf16* ob = o + ((long)b * 196) * 384 + h * 48;
    __builtin_amdgcn_s_setprio(1);
    for (int tt = wid; tt < 39; tt += 4){
        int mi = tt / 13, ni = tt % 13;
        int nB = ni * 16 + lo;
        const __bf16* vrow = base + (long)nB * 1152 + 768;
        f32x4 acc = {};
        #pragma unroll
        for (int e0 = 0; e0 < 64; e0 += 32){
            bf16x8 af = *reinterpret_cast<const bf16x8*>(abf + (mi * 16 + lo) * 72 + e0 + hi * 8);
            bf16x8 bf = *reinterpret_cast<const bf16x8*>(vrow + e0 + hi * 8);
            acc = __builtin_amdgcn_mfma_f32_16x16x32_bf16(af, bf, acc, 0, 0, 0);
        }
        int n = nB;
        if (n < 196){
            #pragma unroll
            for (int j = 0; j < 4; j++){
                int d = mi * 16 + hi * 4 + j;
                ob[(long)n * 384 + d] = (__bf16)acc[j];
            }
        }
    }
    __builtin_amdgcn_s_setprio(0);
}

// ---------------- LPI: gated output to hadd (bf16, [b,n,d]), ht bf16 in ----------------
__global__ __launch_bounds__(256) void lpi_g(const __bf16* __restrict__ ht,
                                             const float* __restrict__ w1, const float* __restrict__ b1,
                                             const float* __restrict__ bng, const float* __restrict__ bnb,
                                             const float* __restrict__ w2, const float* __restrict__ b2,
                                             const float* __restrict__ g3, __bf16* __restrict__ hadd){
    int bd = blockIdx.x;
    int d = bd % 384, b = bd / 384;
    __shared__ float p[16][16];
    __shared__ float p2[16][16];
    __shared__ float wA[9], wB[9];
    int tt = threadIdx.x;
    int yy = tt / 16, xx = tt % 16;
    p[yy][xx] = 0.f; p2[yy][xx] = 0.f;
    if (tt < 9){ wA[tt] = w1[d * 9 + tt]; wB[tt] = w2[d * 9 + tt]; }
    __syncthreads();
    if (tt < 196){
        int y = tt / 14, x = tt % 14;
        p[y + 1][x + 1] = (float)ht[((long)b * 384 + d) * 196 + tt];
    }
    __syncthreads();
    if (tt < 196){
        int y = tt / 14, x = tt % 14;
        float a = 0.f;
        #pragma unroll
        for (int ky = 0; ky < 3; ky++)
            #pragma unroll
            for (int kx = 0; kx < 3; kx++)
                a += wA[ky * 3 + kx] * p[y + ky][x + kx];
        a += b1[d];
        a = gelu_f(a);
        a = a * (bng[d] * rsqrtf(1.0f + 1e-5f)) + bnb[d];
        p2[y + 1][x + 1] = a;
    }
    __syncthreads();
    if (tt < 196){
        int y = tt / 14, x = tt % 14;
        float a = 0.f;
        #pragma unroll
        for (int ky = 0; ky < 3; ky++)
            #pragma unroll
            for (int kx = 0; kx < 3; kx++)
                a += wB[ky * 3 + kx] * p2[y + ky][x + kx];
        a += b2[d];
        hadd[((long)b * 196 + tt) * 384 + d] = (__bf16)(g3[d] * a);
    }
}

// ---------------- cls concat ----------------
__global__ __launch_bounds__(256) void concat_cls(const float* __restrict__ t, const float* __restrict__ clstok,
                                                  float* __restrict__ tc){
    long i = (long)blockIdx.x * 256 + threadIdx.x;
    if (i >= (long)B_ * 197 * 384) return;
    int d = (int)(i % 384);
    long bn = i / 384;
    int n = (int)(bn % 197);
    int b = (int)(bn / 197);
    tc[i] = (n == 0) ? clstok[d] : t[((long)b * 196 + (n - 1)) * 384 + d];
}

// ---------------- CA attention (bf16 qkv) ----------------
__global__ __launch_bounds__(256) void ca_attn(const __bf16* __restrict__ qkv, float* __restrict__ clsp){
    int bh = blockIdx.x;
    int b = bh >> 3, h = bh & 7;
    const __bf16* base = qkv + (long)b * 197 * 1152 + h * 48;
    __shared__ float q0[48];
    __shared__ float at2[197];
    __shared__ float smax, ssum;
    int tid = threadIdx.x;
    if (tid < 48) q0[tid] = (float)base[tid];
    __syncthreads();
    if (tid < 197){
        const __bf16* kr = base + (long)tid * 1152 + 384;
        float s = 0.f;
        for (int d = 0; d < 48; d++) s += q0[d] * (float)kr[d];
        at2[tid] = s * rsqrtf(48.0f);
    }
    __syncthreads();
    if (tid == 0){
        float m = -1e30f;
        for (int n = 0; n < 197; n++) m = fmaxf(m, at2[n]);
        smax = m;
    }
    __syncthreads();
    if (tid < 197) at2[tid] = expf(at2[tid] - smax);
    __syncthreads();
    if (tid == 0){
        float s = 0.f;
        for (int n = 0; n < 197; n++) s += at2[n];
        ssum = s;
    }
    __syncthreads();
    if (tid < 48){
        const __bf16* vb = base + 768 + tid;
        float s = 0.f;
        for (int n = 0; n < 197; n++) s += at2[n] * (float)vb[(long)n * 1152];
        clsp[b * 384 + h * 48 + tid] = s / ssum;
    }
}

__global__ __launch_bounds__(256) void ca_update1(const float* __restrict__ clso, const __bf16* __restrict__ hc,
                                                  const float* __restrict__ g1, float* __restrict__ tc){
    long i = (long)blockIdx.x * 256 + threadIdx.x;
    if (i >= (long)B_ * 197 * 384) return;
    int d = (int)(i % 384);
    long bn = i / 384;
    int n = (int)(bn % 197);
    int b = (int)(bn / 197);
    float add = (n == 0) ? clso[b * 384 + d] : (float)hc[i];
    tc[i] += g1[d] * add;
}

__global__ __launch_bounds__(256) void ca_update2(const float* __restrict__ cls2, const __bf16* __restrict__ hc,
                                                  const float* __restrict__ g2, float* __restrict__ tc){
    long i = (long)blockIdx.x * 256 + threadIdx.x;
    if (i >= (long)B_ * 197 * 384) return;
    int d = (int)(i % 384);
    long bn = i / 384;
    int n = (int)(bn % 197);
    int b = (int)(bn / 197);
    float hv = (float)hc[i];
    tc[i] = (n == 0) ? (g2[d] * cls2[b * 384 + d] + hv) : (hv + hv);
}

extern "C" void kernel_launch(void* const* d_in, const int* in_sizes, int n_in,
                              void* d_out, int out_size, void* d_ws, size_t ws_size,
                              hipStream_t stream){
    (void)in_sizes; (void)n_in; (void)out_size; (void)ws_size;
    const float* x      = (const float*)d_in[0];
    const float* clstok = (const float*)d_in[1];
    const float* pos_w  = (const float*)d_in[2];
    const float* pos_b  = (const float*)d_in[3];
    const float* pe_w[4] = {(const float*)d_in[4], (const float*)d_in[7], (const float*)d_in[10], (const float*)d_in[13]};
    const float* pe_g[4] = {(const float*)d_in[5], (const float*)d_in[8], (const float*)d_in[11], (const float*)d_in[14]};
    const float* pe_b[4] = {(const float*)d_in[6], (const float*)d_in[9], (const float*)d_in[12], (const float*)d_in[15]};
    const float* xqkv_w = (const float*)d_in[16];
    const float* xqkv_b = (const float*)d_in[17];
    const float* xproj_w = (const float*)d_in[18];
    const float* xproj_b = (const float*)d_in[19];
    const float* xtemp  = (const float*)d_in[20];
    const float* xn1_w = (const float*)d_in[21];
    const float* xn1_b = (const float*)d_in[22];
    const float* xn2_w = (const float*)d_in[23];
    const float* xn2_b = (const float*)d_in[24];
    const float* xn3_w = (const float*)d_in[25];
    const float* xn3_b = (const float*)d_in[26];
    const float* xfc1_w = (const float*)d_in[27];
    const float* xfc1_b = (const float*)d_in[28];
    const float* xfc2_w = (const float*)d_in[29];
    const float* xfc2_b = (const float*)d_in[30];
    const float* xlpi1_w = (const float*)d_in[31];
    const float* xlpi1_b = (const float*)d_in[32];
    const float* xlpi2_w = (const float*)d_in[33];
    const float* xlpi2_b = (const float*)d_in[34];
    const float* xbn_g = (const float*)d_in[35];
    const float* xbn_b = (const float*)d_in[36];
    const float* xg1 = (const float*)d_in[37];
    const float* xg2 = (const float*)d_in[38];
    const float* xg3 = (const float*)d_in[39];
    const float* cqkv_w = (const float*)d_in[40];
    const float* cqkv_b = (const float*)d_in[41];
    const float* cproj_w = (const float*)d_in[42];
    const float* cproj_b = (const float*)d_in[43];
    const float* cn1_w = (const float*)d_in[44];
    const float* cn1_b = (const float*)d_in[45];
    const float* cn2_w = (const float*)d_in[46];
    const float* cn2_b = (const float*)d_in[47];
    const float* cfc1_w = (const float*)d_in[48];
    const float* cfc1_b = (const float*)d_in[49];
    const float* cfc2_w = (const float*)d_in[50];
    const float* cfc2_b = (const float*)d_in[51];
    const float* cg1 = (const float*)d_in[52];
    const float* cg2 = (const float*)d_in[53];
    const float* norm_w = (const float*)d_in[54];
    const float* norm_b = (const float*)d_in[55];
    const float* head_w = (const float*)d_in[56];
    const float* head_b = (const float*)d_in[57];
    float* outp = (float*)d_out;

    float* ws = (float*)d_ws;
    // ---- conv phase buffers ----
    __bf16* A1   = (__bf16*)(ws);                  // 401408x32
    __bf16* out1 = (__bf16*)(ws + 7000000L);       // 401408x48
    __bf16* out2 = (__bf16*)(ws + 17000000L);      // 100352x96
    __bf16* out3 = (__bf16*)(ws + 25000000L);      // 25088x192
    __bf16* wcv  = (__bf16*)(ws + 36000000L);
    __bf16* W1c = wcv;
    __bf16* W2c = wcv + 1536;
    __bf16* W3c = wcv + 44544;
    __bf16* W4c = wcv + 216576;
    // ---- XCA phase ----
    __bf16* wqkv_bf = (__bf16*)(ws);
    __bf16* wproj_bf = (__bf16*)(ws + 5308416L);
    __bf16* wfc1_bf = (__bf16*)(ws + 7077888L);
    __bf16* wfc2_bf = (__bf16*)(ws + 14155776L);
    float*  t       = ws + 21233664L;
    float*  pos     = ws + 23642112L;
    __bf16* h_bf    = (__bf16*)(ws + 23717376L);
    __bf16* qkv_bf  = (__bf16*)(ws + 24921600L);
    __bf16* o_bf    = (__bf16*)(ws + 28534272L);
    __bf16* ht_bf   = (__bf16*)(ws + 29738496L);
    __bf16* f1_bf   = (__bf16*)(ws + 32146944L);
    // aliases (time-disjoint within a layer):
    __bf16* o2_bf   = (__bf16*)(ws + 34555392L);
    __bf16* f2_bf   = (__bf16*)(ws + 24921600L);
    __bf16* hadd_bf = (__bf16*)(ws + 28534272L);
    // ---- CA phase ----
    float* tc   = ws;
    __bf16* hc_bf = (__bf16*)(ws + 2420736L);
    __bf16* qkvc_bf = (__bf16*)(ws + 4841472L);
    float* clsp = ws + 8472576L;
    float* clso = clsp + 12288;
    float* f1c  = clso + 12288;
    float* cls2 = f1c + 49152;
    float* clsf = cls2 + 12288;
    __bf16* cqkv_bf  = (__bf16*)(ws + 9000000L);
    __bf16* cproj_bf = (__bf16*)(ws + 9500000L);
    __bf16* cfc1_bf  = (__bf16*)(ws + 9800000L);
    __bf16* cfc2_bf  = (__bf16*)(ws + 10400000L);
    __bf16* headw_bf = (__bf16*)(ws + 11000000L);

    // ---- conv weight prep ----
    wprep<<<(48 * 32 + 255) / 256, 256, 0, stream>>>(pe_w[0], W1c, 48, 3, 32);
    wprep<<<(96 * 448 + 255) / 256, 256, 0, stream>>>(pe_w[1], W2c, 96, 48, 448);
    wprep<<<(192 * 896 + 255) / 256, 256, 0, stream>>>(pe_w[2], W3c, 192, 96, 896);
    wprep<<<(384 * 1728 + 255) / 256, 256, 0, stream>>>(pe_w[3], W4c, 384, 192, 1728);

    // ---- patch embed: conv1 via im2col; conv2/3/4 via implicit-im2col MFMA GEMM ----
    im2col_x<<<1568, 256, 0, stream>>>(x, A1);
    { dim3 g(3136, 1); gemm_conv<1, 0><<<g, 256, 0, stream>>>(A1, 32, W1c, pe_g[0], pe_b[0], out1, 48, nullptr); }
    pos_embed<<<196, 384, 0, stream>>>(pos_w, pos_b, pos);
    { dim3 g(784, 1);
      gemm_cig<1, 0, 48, 112, 112, 56, 56><<<g, 256, 0, stream>>>(out1, 448, W2c, pe_g[1], pe_b[1], out2, 96, nullptr); }
    { dim3 g(196, 2);
      gemm_cig<1, 0, 96, 56, 56, 28, 28><<<g, 256, 0, stream>>>(out2, 896, W3c, pe_g[2], pe_b[2], out3, 192, nullptr); }
    { dim3 g(49, 3);
      gemm_cig<0, 1, 192, 28, 28, 14, 14><<<g, 256, 0, stream>>>(out3, 1728, W4c, pe_g[3], pe_b[3], t, 384, pos); }

    // ---- convert XCA weights to bf16 ----
    {
        long n1 = (long)L_ * 1152 * 384;
        long n2 = (long)L_ * 384 * 384;
        long n3 = (long)L_ * 1536 * 384;
        cvt_bf<<<(int)((n1 + 2047) / 2048), 256, 0, stream>>>(xqkv_w, wqkv_bf, n1);
        cvt_bf<<<(int)((n2 + 2047) / 2048), 256, 0, stream>>>(xproj_w, wproj_bf, n2);
        cvt_bf<<<(int)((n3 + 2047) / 2048), 256, 0, stream>>>(xfc1_w, wfc1_bf, n3);
        cvt_bf<<<(int)((n3 + 2047) / 2048), 256, 0, stream>>>(xfc2_w, wfc2_bf, n3);
    }

    // ---- 24 XCA layers ----
    const int M = B_ * N_;  // 6272 = 98*64
    ln384_bf<<<M, 128, 0, stream>>>(t, xn1_w, xn1_b, h_bf);   // initial LN1
    for (int l = 0; l < L_; l++){
        {
            dim3 g(98, 9);
            gemm_bb2<0, 1, 0, 0, 0><<<g, 256, 0, stream>>>(h_bf, 384, wqkv_bf + (long)l * 1152 * 384, 384,
                                                           xqkv_b + l * 1152, qkv_bf, 1152, 384, M, 0);
        }
        xca2<<<B_ * NH_, 256, 0, stream>>>(qkv_bf, xtemp + l * 8, o_bf);
        {   // proj: 64x64 tiles
            dim3 g(98, 6);
            gemm_bb3<<<g, 256, 0, stream>>>(o_bf, 384, wproj_bf + (long)l * 384 * 384, 384,
                                            xproj_b + l * 384, o2_bf, 384, 384);
        }
        proj_res_lnt<<<M, 128, 0, stream>>>(o2_bf, xg1 + l * 384, t,
                                            xn3_w + l * 384, xn3_b + l * 384, ht_bf);
        lpi_g<<<B_ * D_, 256, 0, stream>>>(ht_bf, xlpi1_w + (long)l * 384 * 9, xlpi1_b + l * 384,
                                           xbn_g + l * 384, xbn_b + l * 384,
                                           xlpi2_w + (long)l * 384 * 9, xlpi2_b + l * 384,
                                           xg3 + l * 384, hadd_bf);
        ln2res<<<M, 128, 0, stream>>>(t, hadd_bf, xn2_w + l * 384, xn2_b + l * 384, h_bf);
        {
            dim3 g(98, 12);
            gemm_bb2<1, 1, 0, 0, 0><<<g, 256, 0, stream>>>(h_bf, 384, wfc1_bf + (long)l * 1536 * 384, 384,
                                                           xfc1_b + l * 1536, f1_bf, 1536, 384, M, 0);
        }
        {   // fc2: 64x64 tiles
            dim3 g(98, 6);
            gemm_bb3<<<g, 256, 0, stream>>>(f1_bf, 1536, wfc2_bf + (long)l * 1536 * 384, 1536,
                                            xfc2_b + l * 384, f2_bf, 384, 1536);
        }
        int ln = (l + 1) % L_;
        fc2_res_ln<<<M, 128, 0, stream>>>(f2_bf, xg2 + l * 384, t,
                                          xn1_w + ln * 384, xn1_b + ln * 384, h_bf);
    }

    // ---- cls concat + 2 CA blocks (bf16 hc) ----
    const long NC = (long)B_ * 197 * 384;
    concat_cls<<<(int)(NC / 256), 256, 0, stream>>>(t, clstok, tc);
    {
        long nc = (long)2 * 1152 * 384;
        cvt_bf<<<(int)((nc + 2047) / 2048), 256, 0, stream>>>(cqkv_w, cqkv_bf, nc);
        long np = (long)2 * 384 * 384;
        cvt_bf<<<(int)((np + 2047) / 2048), 256, 0, stream>>>(cproj_w, cproj_bf, np);
        long nf = (long)2 * 1536 * 384;
        cvt_bf<<<(int)((nf + 2047) / 2048), 256, 0, stream>>>(cfc1_w, cfc1_bf, nf);
        cvt_bf<<<(int)((nf + 2047) / 2048), 256, 0, stream>>>(cfc2_w, cfc2_bf, nf);
        cvt_pad<<<(1024 * 384 + 255) / 256, 256, 0, stream>>>(head_w, headw_bf, 1000, 384, 1024);
    }
    const int MC = B_ * 197;  // 6304
    for (int i = 0; i < 2; i++){
        ln384_bf<<<MC, 128, 0, stream>>>(tc, cn1_w + i * 384, cn1_b + i * 384, hc_bf);
        {
            dim3 g(99, 9);
            gemm_bb2<0, 1, 0, 1, 0><<<g, 256, 0, stream>>>(hc_bf, 384, cqkv_bf + (long)i * 1152 * 384, 384,
                                                           cqkv_b + i * 1152, qkvc_bf, 1152, 384, MC, 0);
        }
        ca_attn<<<B_ * NH_, 256, 0, stream>>>(qkvc_bf, clsp);
        {
            dim3 g(1, 3);
            gemm_bb2<0, 0, 1, 1, 0><<<g, 256, 0, stream>>>(clsp, 384, cproj_bf + (long)i * 384 * 384, 384,
                                                           cproj_b + i * 384, clso, 384, 384, 32, 0);
        }
        ca_update1<<<(int)(NC / 256), 256, 0, stream>>>(clso, hc_bf, cg1 + i * 384, tc);
        ln384_bf<<<MC, 128, 0, stream>>>(tc, cn2_w + i * 384, cn2_b + i * 384, hc_bf);
        {
            dim3 g(1, 12);
            gemm_bb2<1, 0, 0, 1, 0><<<g, 256, 0, stream>>>(hc_bf, (long)197 * 384, cfc1_bf + (long)i * 1536 * 384, 384,
                                                           cfc1_b + i * 1536, f1c, 1536, 384, 32, 0);
        }
        {
            dim3 g(1, 3);
            gemm_bb2<0, 0, 1, 1, 0><<<g, 256, 0, stream>>>(f1c, 1536, cfc2_bf + (long)i * 1536 * 384, 1536,
                                                           cfc2_b + i * 384, cls2, 384, 1536, 32, 0);
        }
        ca_update2<<<(int)(NC / 256), 256, 0, stream>>>(cls2, hc_bf, cg2 + i * 384, tc);
    }

    // ---- final LN (cls token only) + head ----
    ln384<<<32, 128, 0, stream>>>(tc, (long)197 * 384, norm_w, norm_b, clsf, 384);
    {
        dim3 g(1, 8);
        gemm_bb2<0, 0, 1, 1, 1><<<g, 256, 0, stream>>>(clsf, 384, headw_bf, 384,
                                                       head_b, outp, 1000, 384, 32, 1000);
    }
}

// Round 15
// 3673.830 us; speedup vs baseline: 1.0731x; 1.0112x over previous
//
#include <hip/hip_runtime.h>
#include <hip/hip_bf16.h>

#define B_ 32
#define D_ 384
#define N_ 196
#define NH_ 8
#define HD_ 48
#define L_ 24

typedef __bf16 bf16x8 __attribute__((ext_vector_type(8)));
typedef __bf16 bf16x4 __attribute__((ext_vector_type(4)));
typedef float f32x4 __attribute__((ext_vector_type(4)));

__device__ __forceinline__ float gelu_f(float v){
    return 0.5f * v * (1.0f + erff(v * 0.70710678118654752f));
}

// ---------------- fp32 -> bf16 bulk convert ----------------
__global__ __launch_bounds__(256) void cvt_bf(const float* __restrict__ s, __bf16* __restrict__ d, long n){
    long i = ((long)blockIdx.x * 256 + threadIdx.x) * 8;
    if (i >= n) return;
    float4 a = *reinterpret_cast<const float4*>(s + i);
    float4 b = *reinterpret_cast<const float4*>(s + i + 4);
    bf16x8 r;
    r[0] = (__bf16)a.x; r[1] = (__bf16)a.y; r[2] = (__bf16)a.z; r[3] = (__bf16)a.w;
    r[4] = (__bf16)b.x; r[5] = (__bf16)b.y; r[6] = (__bf16)b.z; r[7] = (__bf16)b.w;
    *reinterpret_cast<bf16x8*>(d + i) = r;
}

// fp32 -> bf16 with row padding (zero rows >= rows)
__global__ __launch_bounds__(256) void cvt_pad(const float* __restrict__ s, __bf16* __restrict__ d,
                                               int rows, int K, int rows_pad){
    int id = blockIdx.x * 256 + threadIdx.x;
    if (id >= rows_pad * K) return;
    int r = id / K;
    d[id] = (r < rows) ? (__bf16)s[id] : (__bf16)0.f;
}

// ---------------- conv weight reorder: W'[co][tap*Ci+ci] (bf16, K padded) ----------------
__global__ __launch_bounds__(256) void wprep(const float* __restrict__ w, __bf16* __restrict__ W2,
                                             int Co, int Ci, int Kpad){
    int id = blockIdx.x * 256 + threadIdx.x;
    if (id >= Co * Kpad) return;
    int co = id / Kpad, k = id - co * Kpad;
    float v = 0.f;
    if (k < 9 * Ci){
        int tap = k / Ci, ci = k - tap * Ci;
        v = w[((long)co * Ci + ci) * 9 + tap];
    }
    W2[id] = (__bf16)v;
}

// ---------------- im2col for conv1 (fp32 NCHW input) -> A[pix][32] bf16 ----------------
__global__ __launch_bounds__(256) void im2col_x(const float* __restrict__ x, __bf16* __restrict__ A){
    int id = blockIdx.x * 256 + threadIdx.x;
    if (id >= 401408) return;
    int ox = id % 112; int t1 = id / 112; int oy = t1 % 112; int b = t1 / 112;
    __bf16 buf[32];
    #pragma unroll
    for (int i = 0; i < 32; i++) buf[i] = (__bf16)0.f;
    const float* xb = x + (long)b * 3 * 224 * 224;
    #pragma unroll
    for (int tap = 0; tap < 9; tap++){
        int ky = tap / 3, kx = tap % 3;
        int iy = oy * 2 - 1 + ky, ix = ox * 2 - 1 + kx;
        if ((unsigned)iy < 224u && (unsigned)ix < 224u){
            #pragma unroll
            for (int ci = 0; ci < 3; ci++)
                buf[tap * 3 + ci] = (__bf16)xb[((long)ci * 224 + iy) * 224 + ix];
        }
    }
    __bf16* dst = A + (long)id * 32;
    #pragma unroll
    for (int i = 0; i < 4; i++)
        *reinterpret_cast<bf16x8*>(dst + i * 8) = *reinterpret_cast<bf16x8*>(buf + i * 8);
}

// ---------------- conv GEMM for conv1: 128x128 tile, BK=32, fused BN+GELU ----------------
template<int GELU, int POSOUT>
__global__ __launch_bounds__(256) void gemm_conv(const __bf16* __restrict__ A, int Kpad,
                                                 const __bf16* __restrict__ W,
                                                 const float* __restrict__ g, const float* __restrict__ bb,
                                                 void* __restrict__ Cv, int N,
                                                 const float* __restrict__ pos){
    __shared__ __align__(16) char smem[20480];
    char* Ab = smem;
    char* Bb = smem + 10240;
    const int tid  = threadIdx.x;
    const int lane = tid & 63;
    const int wn   = (tid >> 6) & 1;
    const int wm   = tid >> 7;
    const int row0 = blockIdx.x * 128;
    const int col0 = blockIdx.y * 128;
    const int hi = lane >> 4, lo = lane & 15;
    f32x4 acc[4][4] = {};
    auto loadA = [&](int kk, int i)->bf16x8 {
        int p = i * 256 + tid;
        int r = p >> 2, cq = p & 3;
        return *reinterpret_cast<const bf16x8*>(A + (long)(row0 + r) * Kpad + kk + cq * 8);
    };
    auto loadB = [&](int kk, int i)->bf16x8 {
        int p = i * 256 + tid;
        int r = p >> 2, cq = p & 3;
        int gc = col0 + r;
        bf16x8 vw{};
        if (gc < N) vw = *reinterpret_cast<const bf16x8*>(W + (long)gc * Kpad + kk + cq * 8);
        return vw;
    };
    bf16x8 vaC0 = loadA(0, 0), vaC1 = loadA(0, 1);
    bf16x8 vwC0 = loadB(0, 0), vwC1 = loadB(0, 1);
    for (int k0 = 0; k0 < Kpad; k0 += 32){
        #pragma unroll
        for (int i = 0; i < 2; i++){
            int p = i * 256 + tid;
            int r = p >> 2, cq = p & 3;
            *reinterpret_cast<bf16x8*>(Ab + r * 80 + cq * 16) = i ? vaC1 : vaC0;
            *reinterpret_cast<bf16x8*>(Bb + r * 80 + cq * 16) = i ? vwC1 : vwC0;
        }
        __syncthreads();
        int kn = (k0 + 32 < Kpad) ? k0 + 32 : k0;
        bf16x8 vaN0 = loadA(kn, 0), vaN1 = loadA(kn, 1);
        bf16x8 vwN0 = loadB(kn, 0), vwN1 = loadB(kn, 1);
        bf16x8 af[4], bfr[4];
        #pragma unroll
        for (int m = 0; m < 4; m++)
            af[m] = *reinterpret_cast<const bf16x8*>(Ab + (wm * 64 + m * 16 + lo) * 80 + hi * 16);
        #pragma unroll
        for (int n = 0; n < 4; n++)
            bfr[n] = *reinterpret_cast<const bf16x8*>(Bb + (wn * 64 + n * 16 + lo) * 80 + hi * 16);
        #pragma unroll
        for (int m = 0; m < 4; m++)
            #pragma unroll
            for (int n = 0; n < 4; n++)
                acc[m][n] = __builtin_amdgcn_mfma_f32_16x16x32_bf16(af[m], bfr[n], acc[m][n], 0, 0, 0);
        __syncthreads();
        vaC0 = vaN0; vaC1 = vaN1; vwC0 = vwN0; vwC1 = vwN1;
    }
    float* Cf = (float*)Cv;
    __bf16* Cb = (__bf16*)Cv;
    #pragma unroll
    for (int m = 0; m < 4; m++){
        #pragma unroll
        for (int n = 0; n < 4; n++){
            int row = row0 + wm * 64 + m * 16 + hi * 4;
            int col = col0 + wn * 64 + n * 16 + lo;
            if (col >= N) continue;
            float scale = g[col] * rsqrtf(1.0f + 1e-5f);
            float bv = bb[col];
            #pragma unroll
            for (int j = 0; j < 4; j++){
                float v = acc[m][n][j] * scale + bv;
                if (GELU) v = gelu_f(v);
                if (POSOUT)
                    Cf[(long)(row + j) * 384 + col] = v + pos[((row + j) % 196) * 384 + col];
                else
                    Cb[(long)(row + j) * N + col] = (__bf16)v;
            }
        }
    }
}

// ---------------- implicit-im2col conv GEMM (conv2/3/4): gathers A from [pix][C] bf16 ----------------
template<int GELU, int POSOUT, int C, int Hi, int Wi, int Ho, int Wo>
__global__ __launch_bounds__(256) void gemm_cig(const __bf16* __restrict__ in, int Kpad,
                                                const __bf16* __restrict__ W,
                                                const float* __restrict__ g, const float* __restrict__ bb,
                                                void* __restrict__ Cv, int N,
                                                const float* __restrict__ pos){
    __shared__ __align__(16) char smem[36864];
    char* Ab = smem;
    char* Bb = smem + 18432;
    const int tid  = threadIdx.x;
    const int lane = tid & 63;
    const int wn   = (tid >> 6) & 1;
    const int wm   = tid >> 7;
    const int row0 = blockIdx.x * 128;
    const int col0 = blockIdx.y * 128;
    const int hi = lane >> 4, lo = lane & 15;
    f32x4 acc[4][4] = {};
    auto loadA = [&](int kk, int i)->bf16x8 {
        int p = i * 256 + tid;
        int r = p >> 3, cq = p & 7;
        int koff = kk + cq * 8;
        int tap = koff / C;
        int ci = koff - tap * C;
        bf16x8 va{};
        if (tap < 9){
            int pix = row0 + r;
            int b = pix / (Ho * Wo);
            int rem = pix - b * (Ho * Wo);
            int oy = rem / Wo, ox = rem - oy * Wo;
            int iy = oy * 2 - 1 + tap / 3, ix = ox * 2 - 1 + tap % 3;
            if ((unsigned)iy < (unsigned)Hi && (unsigned)ix < (unsigned)Wi)
                va = *reinterpret_cast<const bf16x8*>(in + (((long)b * Hi + iy) * Wi + ix) * C + ci);
        }
        return va;
    };
    auto loadB = [&](int kk, int i)->bf16x8 {
        int p = i * 256 + tid;
        int r = p >> 3, cq = p & 7;
        int gc = col0 + r;
        bf16x8 vw{};
        if (gc < N) vw = *reinterpret_cast<const bf16x8*>(W + (long)gc * Kpad + kk + cq * 8);
        return vw;
    };
    bf16x8 vaC[4], vwC[4];
    #pragma unroll
    for (int i = 0; i < 4; i++){ vaC[i] = loadA(0, i); vwC[i] = loadB(0, i); }
    for (int k0 = 0; k0 < Kpad; k0 += 64){
        #pragma unroll
        for (int i = 0; i < 4; i++){
            int p = i * 256 + tid;
            int r = p >> 3, cq = p & 7;
            *reinterpret_cast<bf16x8*>(Ab + r * 144 + cq * 16) = vaC[i];
            *reinterpret_cast<bf16x8*>(Bb + r * 144 + cq * 16) = vwC[i];
        }
        __syncthreads();
        int kn = (k0 + 64 < Kpad) ? k0 + 64 : k0;
        bf16x8 vaN[4], vwN[4];
        #pragma unroll
        for (int i = 0; i < 4; i++){ vaN[i] = loadA(kn, i); vwN[i] = loadB(kn, i); }
        bf16x8 af[2][4], bfr[2][4];
        #pragma unroll
        for (int m = 0; m < 4; m++){
            af[0][m] = *reinterpret_cast<const bf16x8*>(Ab + (wm * 64 + m * 16 + lo) * 144 + hi * 16);
            af[1][m] = *reinterpret_cast<const bf16x8*>(Ab + (wm * 64 + m * 16 + lo) * 144 + 64 + hi * 16);
        }
        #pragma unroll
        for (int n = 0; n < 4; n++){
            bfr[0][n] = *reinterpret_cast<const bf16x8*>(Bb + (wn * 64 + n * 16 + lo) * 144 + hi * 16);
            bfr[1][n] = *reinterpret_cast<const bf16x8*>(Bb + (wn * 64 + n * 16 + lo) * 144 + 64 + hi * 16);
        }
        #pragma unroll
        for (int kc = 0; kc < 2; kc++)
            #pragma unroll
            for (int m = 0; m < 4; m++)
                #pragma unroll
                for (int n = 0; n < 4; n++)
                    acc[m][n] = __builtin_amdgcn_mfma_f32_16x16x32_bf16(af[kc][m], bfr[kc][n], acc[m][n], 0, 0, 0);
        __syncthreads();
        #pragma unroll
        for (int i = 0; i < 4; i++){ vaC[i] = vaN[i]; vwC[i] = vwN[i]; }
    }
    float* Cf = (float*)Cv;
    __bf16* Cb = (__bf16*)Cv;
    #pragma unroll
    for (int m = 0; m < 4; m++){
        #pragma unroll
        for (int n = 0; n < 4; n++){
            int row = row0 + wm * 64 + m * 16 + hi * 4;
            int col = col0 + wn * 64 + n * 16 + lo;
            if (col >= N) continue;
            float scale = g[col] * rsqrtf(1.0f + 1e-5f);
            float bv = bb[col];
            #pragma unroll
            for (int j = 0; j < 4; j++){
                float v = acc[m][n][j] * scale + bv;
                if (GELU) v = gelu_f(v);
                if (POSOUT)
                    Cf[(long)(row + j) * 384 + col] = v + pos[((row + j) % 196) * 384 + col];
                else
                    Cb[(long)(row + j) * N + col] = (__bf16)v;
            }
        }
    }
}

// ---------------- LayerNorm over D=384, fp32 out ----------------
__global__ __launch_bounds__(128) void ln384(const float* __restrict__ x, long xstride,
                                             const float* __restrict__ w, const float* __restrict__ b,
                                             float* __restrict__ y, long ystride){
    long row = blockIdx.x;
    int tid = threadIdx.x;
    const float* xr = x + row * xstride;
    float v0 = xr[tid], v1 = xr[tid + 128], v2 = xr[tid + 256];
    float s = v0 + v1 + v2;
    float ss = v0 * v0 + v1 * v1 + v2 * v2;
    for (int off = 32; off; off >>= 1){ s += __shfl_down(s, off); ss += __shfl_down(ss, off); }
    __shared__ float rs[2], rss[2];
    if ((tid & 63) == 0){ rs[tid >> 6] = s; rss[tid >> 6] = ss; }
    __syncthreads();
    float S = rs[0] + rs[1], SS = rss[0] + rss[1];
    float m = S * (1.0f / 384.0f);
    float var = SS * (1.0f / 384.0f) - m * m;
    float r = rsqrtf(var + 1e-5f);
    float* yr = y + row * ystride;
    yr[tid]       = (v0 - m) * r * w[tid]       + b[tid];
    yr[tid + 128] = (v1 - m) * r * w[tid + 128] + b[tid + 128];
    yr[tid + 256] = (v2 - m) * r * w[tid + 256] + b[tid + 256];
}

// ---------------- LayerNorm, bf16 out (row stride 384) ----------------
__global__ __launch_bounds__(128) void ln384_bf(const float* __restrict__ x,
                                                const float* __restrict__ w, const float* __restrict__ b,
                                                __bf16* __restrict__ y){
    long row = blockIdx.x;
    int tid = threadIdx.x;
    const float* xr = x + row * 384;
    float v0 = xr[tid], v1 = xr[tid + 128], v2 = xr[tid + 256];
    float s = v0 + v1 + v2;
    float ss = v0 * v0 + v1 * v1 + v2 * v2;
    for (int off = 32; off; off >>= 1){ s += __shfl_down(s, off); ss += __shfl_down(ss, off); }
    __shared__ float rs[2], rss[2];
    if ((tid & 63) == 0){ rs[tid >> 6] = s; rss[tid >> 6] = ss; }
    __syncthreads();
    float S = rs[0] + rs[1], SS = rss[0] + rss[1];
    float m = S * (1.0f / 384.0f);
    float var = SS * (1.0f / 384.0f) - m * m;
    float r = rsqrtf(var + 1e-5f);
    __bf16* yr = y + row * 384;
    yr[tid]       = (__bf16)((v0 - m) * r * w[tid]       + b[tid]);
    yr[tid + 128] = (__bf16)((v1 - m) * r * w[tid + 128] + b[tid + 128]);
    yr[tid + 256] = (__bf16)((v2 - m) * r * w[tid + 256] + b[tid + 256]);
}

// ---------------- t += g1*o2 ; hn = LN3(t) row-major bf16 ----------------
__global__ __launch_bounds__(128) void proj_res_lnt(const __bf16* __restrict__ o2,
                                                    const float* __restrict__ g1,
                                                    float* __restrict__ t,
                                                    const float* __restrict__ n3w, const float* __restrict__ n3b,
                                                    __bf16* __restrict__ hn){
    long row = blockIdx.x;
    int tid = threadIdx.x;
    int c0 = tid * 4;
    float v[4] = {0.f, 0.f, 0.f, 0.f};
    if (tid < 96){
        float4 tv = *reinterpret_cast<const float4*>(t + row * 384 + c0);
        bf16x4 ov = *reinterpret_cast<const bf16x4*>(o2 + row * 384 + c0);
        v[0] = tv.x + g1[c0 + 0] * (float)ov[0];
        v[1] = tv.y + g1[c0 + 1] * (float)ov[1];
        v[2] = tv.z + g1[c0 + 2] * (float)ov[2];
        v[3] = tv.w + g1[c0 + 3] * (float)ov[3];
        *reinterpret_cast<float4*>(t + row * 384 + c0) = make_float4(v[0], v[1], v[2], v[3]);
    }
    float s = v[0] + v[1] + v[2] + v[3];
    float ss = v[0] * v[0] + v[1] * v[1] + v[2] * v[2] + v[3] * v[3];
    for (int off = 32; off; off >>= 1){ s += __shfl_down(s, off); ss += __shfl_down(ss, off); }
    __shared__ float rs[2], rss[2];
    if ((tid & 63) == 0){ rs[tid >> 6] = s; rss[tid >> 6] = ss; }
    __syncthreads();
    float S = rs[0] + rs[1], SS = rss[0] + rss[1];
    float m = S * (1.0f / 384.0f);
    float var = SS * (1.0f / 384.0f) - m * m;
    float r = rsqrtf(var + 1e-5f);
    if (tid < 96){
        bf16x4 o;
        #pragma unroll
        for (int j = 0; j < 4; j++){
            int c = c0 + j;
            o[j] = (__bf16)((v[j] - m) * r * n3w[c] + n3b[c]);
        }
        *reinterpret_cast<bf16x4*>(hn + row * 384 + c0) = o;
    }
}

// ---------------- t += hadd ; h = LN2(t) bf16 ----------------
__global__ __launch_bounds__(128) void ln2res(float* __restrict__ t,
                                              const __bf16* __restrict__ hadd,
                                              const float* __restrict__ n2w, const float* __restrict__ n2b,
                                              __bf16* __restrict__ h){
    long row = blockIdx.x;
    int tid = threadIdx.x;
    int c0 = tid * 4;
    float v[4] = {0.f, 0.f, 0.f, 0.f};
    if (tid < 96){
        float4 tv = *reinterpret_cast<const float4*>(t + row * 384 + c0);
        bf16x4 hv = *reinterpret_cast<const bf16x4*>(hadd + row * 384 + c0);
        v[0] = tv.x + (float)hv[0];
        v[1] = tv.y + (float)hv[1];
        v[2] = tv.z + (float)hv[2];
        v[3] = tv.w + (float)hv[3];
        *reinterpret_cast<float4*>(t + row * 384 + c0) = make_float4(v[0], v[1], v[2], v[3]);
    }
    float s = v[0] + v[1] + v[2] + v[3];
    float ss = v[0] * v[0] + v[1] * v[1] + v[2] * v[2] + v[3] * v[3];
    for (int off = 32; off; off >>= 1){ s += __shfl_down(s, off); ss += __shfl_down(ss, off); }
    __shared__ float rs[2], rss[2];
    if ((tid & 63) == 0){ rs[tid >> 6] = s; rss[tid >> 6] = ss; }
    __syncthreads();
    float S = rs[0] + rs[1], SS = rss[0] + rss[1];
    float m = S * (1.0f / 384.0f);
    float var = SS * (1.0f / 384.0f) - m * m;
    float r = rsqrtf(var + 1e-5f);
    if (tid < 96){
        bf16x4 o;
        #pragma unroll
        for (int j = 0; j < 4; j++){
            int c = c0 + j;
            o[j] = (__bf16)((v[j] - m) * r * n2w[c] + n2b[c]);
        }
        *reinterpret_cast<bf16x4*>(h + row * 384 + c0) = o;
    }
}

// ---------------- t += g2*f2 ; h = LN1next(t) bf16 ----------------
__global__ __launch_bounds__(128) void fc2_res_ln(const __bf16* __restrict__ f2,
                                                  const float* __restrict__ g2,
                                                  float* __restrict__ t,
                                                  const float* __restrict__ n1w, const float* __restrict__ n1b,
                                                  __bf16* __restrict__ h){
    long row = blockIdx.x;
    int tid = threadIdx.x;
    int c0 = tid * 4;
    float v[4] = {0.f, 0.f, 0.f, 0.f};
    if (tid < 96){
        float4 tv = *reinterpret_cast<const float4*>(t + row * 384 + c0);
        bf16x4 fv = *reinterpret_cast<const bf16x4*>(f2 + row * 384 + c0);
        v[0] = tv.x + g2[c0 + 0] * (float)fv[0];
        v[1] = tv.y + g2[c0 + 1] * (float)fv[1];
        v[2] = tv.z + g2[c0 + 2] * (float)fv[2];
        v[3] = tv.w + g2[c0 + 3] * (float)fv[3];
        *reinterpret_cast<float4*>(t + row * 384 + c0) = make_float4(v[0], v[1], v[2], v[3]);
    }
    float s = v[0] + v[1] + v[2] + v[3];
    float ss = v[0] * v[0] + v[1] * v[1] + v[2] * v[2] + v[3] * v[3];
    for (int off = 32; off; off >>= 1){ s += __shfl_down(s, off); ss += __shfl_down(ss, off); }
    __shared__ float rs[2], rss[2];
    if ((tid & 63) == 0){ rs[tid >> 6] = s; rss[tid >> 6] = ss; }
    __syncthreads();
    float S = rs[0] + rs[1], SS = rss[0] + rss[1];
    float m = S * (1.0f / 384.0f);
    float var = SS * (1.0f / 384.0f) - m * m;
    float r = rsqrtf(var + 1e-5f);
    if (tid < 96){
        bf16x4 o;
        #pragma unroll
        for (int j = 0; j < 4; j++){
            int c = c0 + j;
            o[j] = (__bf16)((v[j] - m) * r * n1w[c] + n1b[c]);
        }
        *reinterpret_cast<bf16x4*>(h + row * 384 + c0) = o;
    }
}

// ---------------- bf16 MFMA GEMM, 64x128 tile, 4 waves, BK=64, 2-stage prefetch ----------------
template<int MODE, int OUTBF, int ACVT, int GUARD, int NGUARD>
__global__ __launch_bounds__(256) void gemm_bb2(const void* __restrict__ Av, long lda,
                                                const __bf16* __restrict__ W, int Kw,
                                                const float* __restrict__ bias,
                                                void* __restrict__ Cv, long ldc,
                                                int K, int M, int Ncols){
    __shared__ __align__(16) char smem[27648];
    char* Ab = smem;            // 64 rows x 144B
    char* Bb = smem + 9216;     // 128 rows x 144B
    const int tid = threadIdx.x;
    const int lane = tid & 63;
    const int wn = tid >> 6;
    const int row0 = blockIdx.x * 64;
    const int col0 = blockIdx.y * 128;
    const int hi = lane >> 4, lo = lane & 15;
    const __bf16* Abf = (const __bf16*)Av;
    const float* Af = (const float*)Av;
    f32x4 acc[4][2] = {};
    auto loadA = [&](int kk, int i)->bf16x8 {
        int p = i * 256 + tid;
        int r = p >> 3, cq = p & 7;
        bf16x8 va{};
        int grow = row0 + r;
        if (!GUARD || grow < M){
            long ai = (long)grow * lda + kk + cq * 8;
            if (ACVT){
                float4 a0 = *reinterpret_cast<const float4*>(Af + ai);
                float4 a1 = *reinterpret_cast<const float4*>(Af + ai + 4);
                va[0] = (__bf16)a0.x; va[1] = (__bf16)a0.y; va[2] = (__bf16)a0.z; va[3] = (__bf16)a0.w;
                va[4] = (__bf16)a1.x; va[5] = (__bf16)a1.y; va[6] = (__bf16)a1.z; va[7] = (__bf16)a1.w;
            } else {
                va = *reinterpret_cast<const bf16x8*>(Abf + ai);
            }
        }
        return va;
    };
    auto loadB = [&](int kk, int i)->bf16x8 {
        int p = i * 256 + tid;
        int r = p >> 3, cq = p & 7;
        return *reinterpret_cast<const bf16x8*>(W + (long)(col0 + r) * Kw + kk + cq * 8);
    };
    bf16x8 vaC[2], vwC[4];
    vaC[0] = loadA(0, 0); vaC[1] = loadA(0, 1);
    #pragma unroll
    for (int i = 0; i < 4; i++) vwC[i] = loadB(0, i);
    for (int k0 = 0; k0 < K; k0 += 64){
        #pragma unroll
        for (int i = 0; i < 2; i++){
            int p = i * 256 + tid;
            int r = p >> 3, cq = p & 7;
            *reinterpret_cast<bf16x8*>(Ab + r * 144 + cq * 16) = vaC[i];
        }
        #pragma unroll
        for (int i = 0; i < 4; i++){
            int p = i * 256 + tid;
            int r = p >> 3, cq = p & 7;
            *reinterpret_cast<bf16x8*>(Bb + r * 144 + cq * 16) = vwC[i];
        }
        __syncthreads();
        int kn = (k0 + 64 < K) ? k0 + 64 : k0;
        bf16x8 vaN[2], vwN[4];
        vaN[0] = loadA(kn, 0); vaN[1] = loadA(kn, 1);
        #pragma unroll
        for (int i = 0; i < 4; i++) vwN[i] = loadB(kn, i);
        bf16x8 af[2][4], bfr[2][2];
        #pragma unroll
        for (int m = 0; m < 4; m++){
            af[0][m] = *reinterpret_cast<const bf16x8*>(Ab + (m * 16 + lo) * 144 + hi * 16);
            af[1][m] = *reinterpret_cast<const bf16x8*>(Ab + (m * 16 + lo) * 144 + 64 + hi * 16);
        }
        #pragma unroll
        for (int n = 0; n < 2; n++){
            bfr[0][n] = *reinterpret_cast<const bf16x8*>(Bb + (wn * 32 + n * 16 + lo) * 144 + hi * 16);
            bfr[1][n] = *reinterpret_cast<const bf16x8*>(Bb + (wn * 32 + n * 16 + lo) * 144 + 64 + hi * 16);
        }
        #pragma unroll
        for (int kc = 0; kc < 2; kc++)
            #pragma unroll
            for (int m = 0; m < 4; m++)
                #pragma unroll
                for (int n = 0; n < 2; n++)
                    acc[m][n] = __builtin_amdgcn_mfma_f32_16x16x32_bf16(af[kc][m], bfr[kc][n], acc[m][n], 0, 0, 0);
        __syncthreads();
        vaC[0] = vaN[0]; vaC[1] = vaN[1];
        #pragma unroll
        for (int i = 0; i < 4; i++) vwC[i] = vwN[i];
    }
    float* Cf = (float*)Cv;
    __bf16* Cb = (__bf16*)Cv;
    #pragma unroll
    for (int m = 0; m < 4; m++){
        #pragma unroll
        for (int n = 0; n < 2; n++){
            int row = row0 + m * 16 + hi * 4;
            int col = col0 + wn * 32 + n * 16 + lo;
            if (NGUARD && col >= Ncols) continue;
            float bv = bias[col];
            #pragma unroll
            for (int j = 0; j < 4; j++){
                if (GUARD && (row + j) >= M) continue;
                float v = acc[m][n][j] + bv;
                if (MODE == 1) v = gelu_f(v);
                long ci = (long)(row + j) * ldc + col;
                if (OUTBF) Cb[ci] = (__bf16)v;
                else Cf[ci] = v;
            }
        }
    }
}

// ---------------- bf16 MFMA GEMM, 64x64 tile, 2x2 waves (32x32/wave), BK=64, bf16 out ----------------
__global__ __launch_bounds__(256) void gemm_bb3(const __bf16* __restrict__ A, long lda,
                                                const __bf16* __restrict__ W, int Kw,
                                                const float* __restrict__ bias,
                                                __bf16* __restrict__ C, long ldc,
                                                int K){
    __shared__ __align__(16) char smem[18432];
    char* Ab = smem;            // 64 rows x 144B
    char* Bb = smem + 9216;     // 64 rows x 144B
    const int tid = threadIdx.x;
    const int lane = tid & 63;
    const int wid = tid >> 6;
    const int wm = wid >> 1, wnn = wid & 1;
    const int row0 = blockIdx.x * 64;
    const int col0 = blockIdx.y * 64;
    const int hi = lane >> 4, lo = lane & 15;
    f32x4 acc[2][2] = {};
    auto loadA = [&](int kk, int i)->bf16x8 {
        int p = i * 256 + tid;
        int r = p >> 3, cq = p & 7;
        return *reinterpret_cast<const bf16x8*>(A + (long)(row0 + r) * lda + kk + cq * 8);
    };
    auto loadB = [&](int kk, int i)->bf16x8 {
        int p = i * 256 + tid;
        int r = p >> 3, cq = p & 7;
        return *reinterpret_cast<const bf16x8*>(W + (long)(col0 + r) * Kw + kk + cq * 8);
    };
    bf16x8 vaC[2], vwC[2];
    vaC[0] = loadA(0, 0); vaC[1] = loadA(0, 1);
    vwC[0] = loadB(0, 0); vwC[1] = loadB(0, 1);
    for (int k0 = 0; k0 < K; k0 += 64){
        #pragma unroll
        for (int i = 0; i < 2; i++){
            int p = i * 256 + tid;
            int r = p >> 3, cq = p & 7;
            *reinterpret_cast<bf16x8*>(Ab + r * 144 + cq * 16) = vaC[i];
            *reinterpret_cast<bf16x8*>(Bb + r * 144 + cq * 16) = vwC[i];
        }
        __syncthreads();
        int kn = (k0 + 64 < K) ? k0 + 64 : k0;
        bf16x8 vaN[2], vwN[2];
        vaN[0] = loadA(kn, 0); vaN[1] = loadA(kn, 1);
        vwN[0] = loadB(kn, 0); vwN[1] = loadB(kn, 1);
        bf16x8 af[2][2], bfr[2][2];
        #pragma unroll
        for (int m = 0; m < 2; m++){
            af[0][m] = *reinterpret_cast<const bf16x8*>(Ab + (wm * 32 + m * 16 + lo) * 144 + hi * 16);
            af[1][m] = *reinterpret_cast<const bf16x8*>(Ab + (wm * 32 + m * 16 + lo) * 144 + 64 + hi * 16);
        }
        #pragma unroll
        for (int n = 0; n < 2; n++){
            bfr[0][n] = *reinterpret_cast<const bf16x8*>(Bb + (wnn * 32 + n * 16 + lo) * 144 + hi * 16);
            bfr[1][n] = *reinterpret_cast<const bf16x8*>(Bb + (wnn * 32 + n * 16 + lo) * 144 + 64 + hi * 16);
        }
        #pragma unroll
        for (int kc = 0; kc < 2; kc++)
            #pragma unroll
            for (int m = 0; m < 2; m++)
                #pragma unroll
                for (int n = 0; n < 2; n++)
                    acc[m][n] = __builtin_amdgcn_mfma_f32_16x16x32_bf16(af[kc][m], bfr[kc][n], acc[m][n], 0, 0, 0);
        __syncthreads();
        vaC[0] = vaN[0]; vaC[1] = vaN[1]; vwC[0] = vwN[0]; vwC[1] = vwN[1];
    }
    #pragma unroll
    for (int m = 0; m < 2; m++){
        #pragma unroll
        for (int n = 0; n < 2; n++){
            int row = row0 + wm * 32 + m * 16 + hi * 4;
            int col = col0 + wnn * 32 + n * 16 + lo;
            float bv = bias[col];
            #pragma unroll
            for (int j = 0; j < 4; j++)
                C[(long)(row + j) * ldc + col] = (__bf16)(acc[m][n][j] + bv);
        }
    }
}

// ---------------- positional embedding: pos[n, d] ----------------
__global__ __launch_bounds__(384) void pos_embed(const float* __restrict__ pw, const float* __restrict__ pb,
                                                 float* __restrict__ pos){
    __shared__ float p64[64];
    int n = blockIdx.x;
    int iy = n / 14, ix = n % 14;
    int t = threadIdx.x;
    if (t < 64){
        int axis = t >> 5;
        int c = t & 31;
        int u = c >> 1;
        float coord = (axis == 0) ? (float)(iy + 1) : (float)(ix + 1);
        float val = coord / ((14.0f + 1e-6f) * 6.283185307179586f);
        float T = powf(10000.0f, (float)u / 16.0f);
        float a = val / T;
        p64[t] = (c & 1) ? cosf(a) : sinf(a);
    }
    __syncthreads();
    float acc = 0.f;
    const float* wr = pw + (long)t * 64;
    #pragma unroll 8
    for (int c = 0; c < 64; c++) acc += p64[c] * wr[c];
    pos[n * 384 + t] = acc + pb[t];
}

// ---------------- XCA attention via MFMA: one block per (b, head); V read from global ----------------
__global__ __launch_bounds__(256) void xca2(const __bf16* __restrict__ qkv, const float* __restrict__ temp,
                                            __bf16* __restrict__ o){
    __shared__ __align__(16) char smem[45056];
    __bf16* qs = (__bf16*)smem;                 // 48*232*2 = 22272
    __bf16* ks = (__bf16*)(smem + 22272);       // 22272
    float* inq = (float*)(smem + 44544);        // 192
    float* ink = (float*)(smem + 44736);        // 192
    float* att = (float*)smem;                  // overlay on qs (13056B)
    __bf16* abf = (__bf16*)(smem + 22272);      // overlay on ks (6912B)
    int bh = blockIdx.x;
    int b = bh >> 3, h = bh & 7;
    const int tid = threadIdx.x;
    const int wid = tid >> 6, lane = tid & 63;
    const int hi = lane >> 4, lo = lane & 15;
    const __bf16* base = qkv + ((long)b * 196) * 1152 + h * 48;
    bf16x8 z8 = {};
    for (int idx = tid; idx < 48 * 28; idx += 256){
        int d = idx / 28, n = 196 + idx % 28;
        qs[d * 232 + n] = (__bf16)0.f;
        ks[d * 232 + n] = (__bf16)0.f;
    }
    for (int ch = tid; ch < 196 * 6; ch += 256){
        int n = ch / 6, c = ch % 6, d0 = c * 8;
        bf16x8 q8 = *reinterpret_cast<const bf16x8*>(base + (long)n * 1152 + d0);
        bf16x8 k8 = *reinterpret_cast<const bf16x8*>(base + (long)n * 1152 + 384 + d0);
        #pragma unroll
        for (int j = 0; j < 8; j++){
            qs[(d0 + j) * 232 + n] = q8[j];
            ks[(d0 + j) * 232 + n] = k8[j];
        }
    }
    __syncthreads();
    // row norms: vectorized bf16x4 LDS reads (cols 196..223 are zero)
    for (int r = wid; r < 48; r += 4){
        float sq = 0.f, sk = 0.f;
        if (lane < 56){
            bf16x4 q4 = *reinterpret_cast<const bf16x4*>(qs + r * 232 + lane * 4);
            bf16x4 k4 = *reinterpret_cast<const bf16x4*>(ks + r * 232 + lane * 4);
            #pragma unroll
            for (int j = 0; j < 4; j++){
                float qv = (float)q4[j], kv = (float)k4[j];
                sq += qv * qv; sk += kv * kv;
            }
        }
        for (int off = 32; off; off >>= 1){ sq += __shfl_down(sq, off); sk += __shfl_down(sk, off); }
        if (lane == 0){
            inq[r] = 1.0f / fmaxf(sqrtf(sq), 1e-12f);
            ink[r] = 1.0f / fmaxf(sqrtf(sk), 1e-12f);
        }
    }
    __syncthreads();
    float tempv = temp[h];
    f32x4 qk0 = {}, qk1 = {}, qk2 = {};
    __builtin_amdgcn_s_setprio(1);
    {
        int mi = wid / 3, ni = wid % 3;
        #pragma unroll
        for (int k0 = 0; k0 < 224; k0 += 32){
            bf16x8 af = *reinterpret_cast<const bf16x8*>(qs + (mi * 16 + lo) * 232 + k0 + hi * 8);
            bf16x8 bf = *reinterpret_cast<const bf16x8*>(ks + (ni * 16 + lo) * 232 + k0 + hi * 8);
            qk0 = __builtin_amdgcn_mfma_f32_16x16x32_bf16(af, bf, qk0, 0, 0, 0);
        }
    }
    {
        int tt = wid + 4;
        int mi = tt / 3, ni = tt % 3;
        #pragma unroll
        for (int k0 = 0; k0 < 224; k0 += 32){
            bf16x8 af = *reinterpret_cast<const bf16x8*>(qs + (mi * 16 + lo) * 232 + k0 + hi * 8);
            bf16x8 bf = *reinterpret_cast<const bf16x8*>(ks + (ni * 16 + lo) * 232 + k0 + hi * 8);
            qk1 = __builtin_amdgcn_mfma_f32_16x16x32_bf16(af, bf, qk1, 0, 0, 0);
        }
    }
    if (wid == 0){
        #pragma unroll
        for (int k0 = 0; k0 < 224; k0 += 32){
            bf16x8 af = *reinterpret_cast<const bf16x8*>(qs + (2 * 16 + lo) * 232 + k0 + hi * 8);
            bf16x8 bf = *reinterpret_cast<const bf16x8*>(ks + (2 * 16 + lo) * 232 + k0 + hi * 8);
            qk2 = __builtin_amdgcn_mfma_f32_16x16x32_bf16(af, bf, qk2, 0, 0, 0);
        }
    }
    __builtin_amdgcn_s_setprio(0);
    __syncthreads();   // qs/ks reads done; overlays writable
    {
        int mi = wid / 3, ni = wid % 3;
        int e = ni * 16 + lo;
        float se = ink[e] * tempv;
        #pragma unroll
        for (int j = 0; j < 4; j++){
            int d = mi * 16 + hi * 4 + j;
            att[d * 68 + e] = qk0[j] * inq[d] * se;
        }
    }
    {
        int tt = wid + 4;
        int mi = tt / 3, ni = tt % 3;
        int e = ni * 16 + lo;
        float se = ink[e] * tempv;
        #pragma unroll
        for (int j = 0; j < 4; j++){
            int d = mi * 16 + hi * 4 + j;
            att[d * 68 + e] = qk1[j] * inq[d] * se;
        }
    }
    if (wid == 0){
        int e = 2 * 16 + lo;
        float se = ink[e] * tempv;
        #pragma unroll
        for (int j = 0; j < 4; j++){
            int d = 2 * 16 + hi * 4 + j;
            att[d * 68 + e] = qk2[j] * inq[d] * se;
        }
    }
    __syncthreads();
    if (tid < 192){
        int r = tid >> 2, q4 = tid & 3;
        const float* row = att + r * 68 + q4 * 12;
        float mx = -1e30f;
        #pragma unroll
        for (int i = 0; i < 12; i++) mx = fmaxf(mx, row[i]);
        mx = fmaxf(mx, __shfl_xor(mx, 1));
        mx = fmaxf(mx, __shfl_xor(mx, 2));
        float pv[12]; float sm = 0.f;
        #pragma unroll
        for (int i = 0; i < 12; i++){ pv[i] = expf(row[i] - mx); sm += pv[i]; }
        sm += __shfl_xor(sm, 1);
        sm += __shfl_xor(sm, 2);
        float inv = 1.0f / sm;
        #pragma unroll
        for (int i = 0; i < 12; i++) abf[r * 72 + q4 * 12 + i] = (__bf16)(pv[i] * inv);
    }
    for (int idx = tid; idx < 48 * 3; idx += 256){
        int r = idx / 3, c = 48 + (idx % 3) * 8;
        *reinterpret_cast<bf16x8*>(abf + r * 72 + c) = z8;
    }
    __syncthreads();
    // PV: A = abf (LDS), B = V from global (qkv[n][768+e], contiguous in e).
    __bf16* ob = o + ((long)b * 196) * 384 + h * 48;
    __builtin_amdgcn_s_setprio(1);
    for (int tt = wid; tt < 39; tt += 4){
        int mi = tt / 13, ni = tt % 13;
        int nB = ni * 16 + lo;
        const __bf16* vrow = base + (long)nB * 1152 + 768;
        f32x4 acc = {};
        #pragma unroll
        for (int e0 = 0; e0 < 64; e0 += 32){
            bf16x8 af = *reinterpret_cast<const bf16x8*>(abf + (mi * 16 + lo) * 72 + e0 + hi * 8);
            bf16x8 bf = *reinterpret_cast<const bf16x8*>(vrow + e0 + hi * 8);
            acc = __builtin_amdgcn_mfma_f32_16x16x32_bf16(af, bf, acc, 0, 0, 0);
        }
        int n = nB;
        if (n < 196){
            #pragma unroll
            for (int j = 0; j < 4; j++){
                int d = mi * 16 + hi * 4 + j;
                ob[(long)n * 384 + d] = (__bf16)acc[j];
            }
        }
    }
    __builtin_amdgcn_s_setprio(0);
}

// ---------------- LPI in [n,d] layout: block = (b, 32-channel tile), fully coalesced ----------------
// hn: LN3 output [6272][384] bf16. hadd out [6272][384] bf16 (gated).
__global__ __launch_bounds__(256) void lpi_n(const __bf16* __restrict__ hn,
                                             const float* __restrict__ w1, const float* __restrict__ b1,
                                             const float* __restrict__ bng, const float* __restrict__ bnb,
                                             const float* __restrict__ w2, const float* __restrict__ b2,
                                             const float* __restrict__ g3, __bf16* __restrict__ hadd){
    __shared__ float pin[196][33];
    __shared__ float pmid[196][33];
    __shared__ float wA[9][32], wB[9][32];
    __shared__ float c1[32], cg[32], cb[32], c2[32], c3[32];
    int blk = blockIdx.x;
    int b = blk / 12, dt = blk % 12;
    int d0 = dt * 32;
    const int tid = threadIdx.x;
    const int dl = tid & 31;
    const int grp = tid >> 5;   // 0..7
    const int d = d0 + dl;
    for (int i = tid; i < 288; i += 256){
        int c = i & 31, k = i >> 5;
        wA[k][c] = w1[(d0 + c) * 9 + k];
        wB[k][c] = w2[(d0 + c) * 9 + k];
    }
    if (tid < 32){
        c1[tid] = b1[d0 + tid];
        cg[tid] = bng[d0 + tid] * rsqrtf(1.0f + 1e-5f);
        cb[tid] = bnb[d0 + tid];
        c2[tid] = b2[d0 + tid];
        c3[tid] = g3[d0 + tid];
    }
    for (int n = grp; n < 196; n += 8)
        pin[n][dl] = (float)hn[((long)b * 196 + n) * 384 + d];
    __syncthreads();
    for (int n = grp; n < 196; n += 8){
        int y = n / 14, x = n % 14;
        float a = 0.f;
        #pragma unroll
        for (int ky = 0; ky < 3; ky++){
            int yy = y + ky - 1;
            if ((unsigned)yy >= 14u) continue;
            #pragma unroll
            for (int kx = 0; kx < 3; kx++){
                int xx = x + kx - 1;
                if ((unsigned)xx >= 14u) continue;
                a += wA[ky * 3 + kx][dl] * pin[yy * 14 + xx][dl];
            }
        }
        a += c1[dl];
        a = gelu_f(a);
        a = a * cg[dl] + cb[dl];
        pmid[n][dl] = a;
    }
    __syncthreads();
    for (int n = grp; n < 196; n += 8){
        int y = n / 14, x = n % 14;
        float a = 0.f;
        #pragma unroll
        for (int ky = 0; ky < 3; ky++){
            int yy = y + ky - 1;
            if ((unsigned)yy >= 14u) continue;
            #pragma unroll
            for (int kx = 0; kx < 3; kx++){
                int xx = x + kx - 1;
                if ((unsigned)xx >= 14u) continue;
                a += wB[ky * 3 + kx][dl] * pmid[yy * 14 + xx][dl];
            }
        }
        a += c2[dl];
        hadd[((long)b * 196 + n) * 384 + d] = (__bf16)(c3[dl] * a);
    }
}

// ---------------- cls concat ----------------
__global__ __launch_bounds__(256) void concat_cls(const float* __restrict__ t, const float* __restrict__ clstok,
                                                  float* __restrict__ tc){
    long i = (long)blockIdx.x * 256 + threadIdx.x;
    if (i >= (long)B_ * 197 * 384) return;
    int d = (int)(i % 384);
    long bn = i / 384;
    int n = (int)(bn % 197);
    int b = (int)(bn / 197);
    tc[i] = (n == 0) ? clstok[d] : t[((long)b * 196 + (n - 1)) * 384 + d];
}

// ---------------- CA attention (bf16 qkv) ----------------
__global__ __launch_bounds__(256) void ca_attn(const __bf16* __restrict__ qkv, float* __restrict__ clsp){
    int bh = blockIdx.x;
    int b = bh >> 3, h = bh & 7;
    const __bf16* base = qkv + (long)b * 197 * 1152 + h * 48;
    __shared__ float q0[48];
    __shared__ float at2[197];
    __shared__ float smax, ssum;
    int tid = threadIdx.x;
    if (tid < 48) q0[tid] = (float)base[tid];
    __syncthreads();
    if (tid < 197){
        const __bf16* kr = base + (long)tid * 1152 + 384;
        float s = 0.f;
        for (int d = 0; d < 48; d++) s += q0[d] * (float)kr[d];
        at2[tid] = s * rsqrtf(48.0f);
    }
    __syncthreads();
    if (tid == 0){
        float m = -1e30f;
        for (int n = 0; n < 197; n++) m = fmaxf(m, at2[n]);
        smax = m;
    }
    __syncthreads();
    if (tid < 197) at2[tid] = expf(at2[tid] - smax);
    __syncthreads();
    if (tid == 0){
        float s = 0.f;
        for (int n = 0; n < 197; n++) s += at2[n];
        ssum = s;
    }
    __syncthreads();
    if (tid < 48){
        const __bf16* vb = base + 768 + tid;
        float s = 0.f;
        for (int n = 0; n < 197; n++) s += at2[n] * (float)vb[(long)n * 1152];
        clsp[b * 384 + h * 48 + tid] = s / ssum;
    }
}

__global__ __launch_bounds__(256) void ca_update1(const float* __restrict__ clso, const __bf16* __restrict__ hc,
                                                  const float* __restrict__ g1, float* __restrict__ tc){
    long i = (long)blockIdx.x * 256 + threadIdx.x;
    if (i >= (long)B_ * 197 * 384) return;
    int d = (int)(i % 384);
    long bn = i / 384;
    int n = (int)(bn % 197);
    int b = (int)(bn / 197);
    float add = (n == 0) ? clso[b * 384 + d] : (float)hc[i];
    tc[i] += g1[d] * add;
}

__global__ __launch_bounds__(256) void ca_update2(const float* __restrict__ cls2, const __bf16* __restrict__ hc,
                                                  const float* __restrict__ g2, float* __restrict__ tc){
    long i = (long)blockIdx.x * 256 + threadIdx.x;
    if (i >= (long)B_ * 197 * 384) return;
    int d = (int)(i % 384);
    long bn = i / 384;
    int n = (int)(bn % 197);
    int b = (int)(bn / 197);
    float hv = (float)hc[i];
    tc[i] = (n == 0) ? (g2[d] * cls2[b * 384 + d] + hv) : (hv + hv);
}

extern "C" void kernel_launch(void* const* d_in, const int* in_sizes, int n_in,
                              void* d_out, int out_size, void* d_ws, size_t ws_size,
                              hipStream_t stream){
    (void)in_sizes; (void)n_in; (void)out_size; (void)ws_size;
    const float* x      = (const float*)d_in[0];
    const float* clstok = (const float*)d_in[1];
    const float* pos_w  = (const float*)d_in[2];
    const float* pos_b  = (const float*)d_in[3];
    const float* pe_w[4] = {(const float*)d_in[4], (const float*)d_in[7], (const float*)d_in[10], (const float*)d_in[13]};
    const float* pe_g[4] = {(const float*)d_in[5], (const float*)d_in[8], (const float*)d_in[11], (const float*)d_in[14]};
    const float* pe_b[4] = {(const float*)d_in[6], (const float*)d_in[9], (const float*)d_in[12], (const float*)d_in[15]};
    const float* xqkv_w = (const float*)d_in[16];
    const float* xqkv_b = (const float*)d_in[17];
    const float* xproj_w = (const float*)d_in[18];
    const float* xproj_b = (const float*)d_in[19];
    const float* xtemp  = (const float*)d_in[20];
    const float* xn1_w = (const float*)d_in[21];
    const float* xn1_b = (const float*)d_in[22];
    const float* xn2_w = (const float*)d_in[23];
    const float* xn2_b = (const float*)d_in[24];
    const float* xn3_w = (const float*)d_in[25];
    const float* xn3_b = (const float*)d_in[26];
    const float* xfc1_w = (const float*)d_in[27];
    const float* xfc1_b = (const float*)d_in[28];
    const float* xfc2_w = (const float*)d_in[29];
    const float* xfc2_b = (const float*)d_in[30];
    const float* xlpi1_w = (const float*)d_in[31];
    const float* xlpi1_b = (const float*)d_in[32];
    const float* xlpi2_w = (const float*)d_in[33];
    const float* xlpi2_b = (const float*)d_in[34];
    const float* xbn_g = (const float*)d_in[35];
    const float* xbn_b = (const float*)d_in[36];
    const float* xg1 = (const float*)d_in[37];
    const float* xg2 = (const float*)d_in[38];
    const float* xg3 = (const float*)d_in[39];
    const float* cqkv_w = (const float*)d_in[40];
    const float* cqkv_b = (const float*)d_in[41];
    const float* cproj_w = (const float*)d_in[42];
    const float* cproj_b = (const float*)d_in[43];
    const float* cn1_w = (const float*)d_in[44];
    const float* cn1_b = (const float*)d_in[45];
    const float* cn2_w = (const float*)d_in[46];
    const float* cn2_b = (const float*)d_in[47];
    const float* cfc1_w = (const float*)d_in[48];
    const float* cfc1_b = (const float*)d_in[49];
    const float* cfc2_w = (const float*)d_in[50];
    const float* cfc2_b = (const float*)d_in[51];
    const float* cg1 = (const float*)d_in[52];
    const float* cg2 = (const float*)d_in[53];
    const float* norm_w = (const float*)d_in[54];
    const float* norm_b = (const float*)d_in[55];
    const float* head_w = (const float*)d_in[56];
    const float* head_b = (const float*)d_in[57];
    float* outp = (float*)d_out;

    float* ws = (float*)d_ws;
    // ---- conv phase buffers ----
    __bf16* A1   = (__bf16*)(ws);                  // 401408x32
    __bf16* out1 = (__bf16*)(ws + 7000000L);       // 401408x48
    __bf16* out2 = (__bf16*)(ws + 17000000L);      // 100352x96
    __bf16* out3 = (__bf16*)(ws + 25000000L);      // 25088x192
    __bf16* wcv  = (__bf16*)(ws + 36000000L);
    __bf16* W1c = wcv;
    __bf16* W2c = wcv + 1536;
    __bf16* W3c = wcv + 44544;
    __bf16* W4c = wcv + 216576;
    // ---- XCA phase ----
    __bf16* wqkv_bf = (__bf16*)(ws);
    __bf16* wproj_bf = (__bf16*)(ws + 5308416L);
    __bf16* wfc1_bf = (__bf16*)(ws + 7077888L);
    __bf16* wfc2_bf = (__bf16*)(ws + 14155776L);
    float*  t       = ws + 21233664L;
    float*  pos     = ws + 23642112L;
    __bf16* h_bf    = (__bf16*)(ws + 23717376L);
    __bf16* qkv_bf  = (__bf16*)(ws + 24921600L);
    __bf16* o_bf    = (__bf16*)(ws + 28534272L);
    __bf16* hn_bf   = (__bf16*)(ws + 29738496L);
    __bf16* f1_bf   = (__bf16*)(ws + 32146944L);
    // aliases (time-disjoint within a layer):
    __bf16* o2_bf   = (__bf16*)(ws + 34555392L);
    __bf16* f2_bf   = (__bf16*)(ws + 24921600L);
    __bf16* hadd_bf = (__bf16*)(ws + 28534272L);
    // ---- CA phase ----
    float* tc   = ws;
    __bf16* hc_bf = (__bf16*)(ws + 2420736L);
    __bf16* qkvc_bf = (__bf16*)(ws + 4841472L);
    float* clsp = ws + 8472576L;
    float* clso = clsp + 12288;
    float* f1c  = clso + 12288;
    float* cls2 = f1c + 49152;
    float* clsf = cls2 + 12288;
    __bf16* cqkv_bf  = (__bf16*)(ws + 9000000L);
    __bf16* cproj_bf = (__bf16*)(ws + 9500000L);
    __bf16* cfc1_bf  = (__bf16*)(ws + 9800000L);
    __bf16* cfc2_bf  = (__bf16*)(ws + 10400000L);
    __bf16* headw_bf = (__bf16*)(ws + 11000000L);

    // ---- conv weight prep ----
    wprep<<<(48 * 32 + 255) / 256, 256, 0, stream>>>(pe_w[0], W1c, 48, 3, 32);
    wprep<<<(96 * 448 + 255) / 256, 256, 0, stream>>>(pe_w[1], W2c, 96, 48, 448);
    wprep<<<(192 * 896 + 255) / 256, 256, 0, stream>>>(pe_w[2], W3c, 192, 96, 896);
    wprep<<<(384 * 1728 + 255) / 256, 256, 0, stream>>>(pe_w[3], W4c, 384, 192, 1728);

    // ---- patch embed: conv1 via im2col; conv2/3/4 via implicit-im2col MFMA GEMM ----
    im2col_x<<<1568, 256, 0, stream>>>(x, A1);
    { dim3 g(3136, 1); gemm_conv<1, 0><<<g, 256, 0, stream>>>(A1, 32, W1c, pe_g[0], pe_b[0], out1, 48, nullptr); }
    pos_embed<<<196, 384, 0, stream>>>(pos_w, pos_b, pos);
    { dim3 g(784, 1);
      gemm_cig<1, 0, 48, 112, 112, 56, 56><<<g, 256, 0, stream>>>(out1, 448, W2c, pe_g[1], pe_b[1], out2, 96, nullptr); }
    { dim3 g(196, 2);
      gemm_cig<1, 0, 96, 56, 56, 28, 28><<<g, 256, 0, stream>>>(out2, 896, W3c, pe_g[2], pe_b[2], out3, 192, nullptr); }
    { dim3 g(49, 3);
      gemm_cig<0, 1, 192, 28, 28, 14, 14><<<g, 256, 0, stream>>>(out3, 1728, W4c, pe_g[3], pe_b[3], t, 384, pos); }

    // ---- convert XCA weights to bf16 ----
    {
        long n1 = (long)L_ * 1152 * 384;
        long n2 = (long)L_ * 384 * 384;
        long n3 = (long)L_ * 1536 * 384;
        cvt_bf<<<(int)((n1 + 2047) / 2048), 256, 0, stream>>>(xqkv_w, wqkv_bf, n1);
        cvt_bf<<<(int)((n2 + 2047) / 2048), 256, 0, stream>>>(xproj_w, wproj_bf, n2);
        cvt_bf<<<(int)((n3 + 2047) / 2048), 256, 0, stream>>>(xfc1_w, wfc1_bf, n3);
        cvt_bf<<<(int)((n3 + 2047) / 2048), 256, 0, stream>>>(xfc2_w, wfc2_bf, n3);
    }

    // ---- 24 XCA layers ----
    const int M = B_ * N_;  // 6272 = 98*64
    ln384_bf<<<M, 128, 0, stream>>>(t, xn1_w, xn1_b, h_bf);   // initial LN1
    for (int l = 0; l < L_; l++){
        {
            dim3 g(98, 9);
            gemm_bb2<0, 1, 0, 0, 0><<<g, 256, 0, stream>>>(h_bf, 384, wqkv_bf + (long)l * 1152 * 384, 384,
                                                           xqkv_b + l * 1152, qkv_bf, 1152, 384, M, 0);
        }
        xca2<<<B_ * NH_, 256, 0, stream>>>(qkv_bf, xtemp + l * 8, o_bf);
        {   // proj: 64x64 tiles
            dim3 g(98, 6);
            gemm_bb3<<<g, 256, 0, stream>>>(o_bf, 384, wproj_bf + (long)l * 384 * 384, 384,
                                            xproj_b + l * 384, o2_bf, 384, 384);
        }
        proj_res_lnt<<<M, 128, 0, stream>>>(o2_bf, xg1 + l * 384, t,
                                            xn3_w + l * 384, xn3_b + l * 384, hn_bf);
        lpi_n<<<B_ * 12, 256, 0, stream>>>(hn_bf, xlpi1_w + (long)l * 384 * 9, xlpi1_b + l * 384,
                                           xbn_g + l * 384, xbn_b + l * 384,
                                           xlpi2_w + (long)l * 384 * 9, xlpi2_b + l * 384,
                                           xg3 + l * 384, hadd_bf);
        ln2res<<<M, 128, 0, stream>>>(t, hadd_bf, xn2_w + l * 384, xn2_b + l * 384, h_bf);
        {
            dim3 g(98, 12);
            gemm_bb2<1, 1, 0, 0, 0><<<g, 256, 0, stream>>>(h_bf, 384, wfc1_bf + (long)l * 1536 * 384, 384,
                                                           xfc1_b + l * 1536, f1_bf, 1536, 384, M, 0);
        }
        {   // fc2: 64x64 tiles
            dim3 g(98, 6);
            gemm_bb3<<<g, 256, 0, stream>>>(f1_bf, 1536, wfc2_bf + (long)l * 1536 * 384, 1536,
                                            xfc2_b + l * 384, f2_bf, 384, 1536);
        }
        int ln = (l + 1) % L_;
        fc2_res_ln<<<M, 128, 0, stream>>>(f2_bf, xg2 + l * 384, t,
                                          xn1_w + ln * 384, xn1_b + ln * 384, h_bf);
    }

    // ---- cls concat + 2 CA blocks (bf16 hc) ----
    const long NC = (long)B_ * 197 * 384;
    concat_cls<<<(int)(NC / 256), 256, 0, stream>>>(t, clstok, tc);
    {
        long nc = (long)2 * 1152 * 384;
        cvt_bf<<<(int)((nc + 2047) / 2048), 256, 0, stream>>>(cqkv_w, cqkv_bf, nc);
        long np = (long)2 * 384 * 384;
        cvt_bf<<<(int)((np + 2047) / 2048), 256, 0, stream>>>(cproj_w, cproj_bf, np);
        long nf = (long)2 * 1536 * 384;
        cvt_bf<<<(int)((nf + 2047) / 2048), 256, 0, stream>>>(cfc1_w, cfc1_bf, nf);
        cvt_bf<<<(int)((nf + 2047) / 2048), 256, 0, stream>>>(cfc2_w, cfc2_bf, nf);
        cvt_pad<<<(1024 * 384 + 255) / 256, 256, 0, stream>>>(head_w, headw_bf, 1000, 384, 1024);
    }
    const int MC = B_ * 197;  // 6304
    for (int i = 0; i < 2; i++){
        ln384_bf<<<MC, 128, 0, stream>>>(tc, cn1_w + i * 384, cn1_b + i * 384, hc_bf);
        {
            dim3 g(99, 9);
            gemm_bb2<0, 1, 0, 1, 0><<<g, 256, 0, stream>>>(hc_bf, 384, cqkv_bf + (long)i * 1152 * 384, 384,
                                                           cqkv_b + i * 1152, qkvc_bf, 1152, 384, MC, 0);
        }
        ca_attn<<<B_ * NH_, 256, 0, stream>>>(qkvc_bf, clsp);
        {
            dim3 g(1, 3);
            gemm_bb2<0, 0, 1, 1, 0><<<g, 256, 0, stream>>>(clsp, 384, cproj_bf + (long)i * 384 * 384, 384,
                                                           cproj_b + i * 384, clso, 384, 384, 32, 0);
        }
        ca_update1<<<(int)(NC / 256), 256, 0, stream>>>(clso, hc_bf, cg1 + i * 384, tc);
        ln384_bf<<<MC, 128, 0, stream>>>(tc, cn2_w + i * 384, cn2_b + i * 384, hc_bf);
        {
            dim3 g(1, 12);
            gemm_bb2<1, 0, 0, 1, 0><<<g, 256, 0, stream>>>(hc_bf, (long)197 * 384, cfc1_bf + (long)i * 1536 * 384, 384,
                                                           cfc1_b + i * 1536, f1c, 1536, 384, 32, 0);
        }
        {
            dim3 g(1, 3);
            gemm_bb2<0, 0, 1, 1, 0><<<g, 256, 0, stream>>>(f1c, 1536, cfc2_bf + (long)i * 1536 * 384, 1536,
                                                           cfc2_b + i * 384, cls2, 384, 1536, 32, 0);
        }
        ca_update2<<<(int)(NC / 256), 256, 0, stream>>>(cls2, hc_bf, cg2 + i * 384, tc);
    }

    // ---- final LN (cls token only) + head ----
    ln384<<<32, 128, 0, stream>>>(tc, (long)197 * 384, norm_w, norm_b, clsf, 384);
    {
        dim3 g(1, 8);
        gemm_bb2<0, 0, 1, 1, 1><<<g, 256, 0, stream>>>(clsf, 384, headw_bf, 384,
                                                       head_b, outp, 1000, 384, 32, 1000);
    }
}